// Round 1
// baseline (637.693 us; speedup 1.0000x reference)
//
#include <hip/hip_runtime.h>
#include <cstddef>

namespace {
constexpr int B_  = 2;
constexpr int INC = 256;
constexpr int KQn = 128;
constexpr int Hn  = 128;
constexpr int Wn  = 128;
constexpr int HW  = Hn * Wn;        // 16384
constexpr int NTOT = 21504;         // 16384 + 4096 + 1024
constexpr float SCALE = 0.088388347648318447f;  // 128^-0.5
}

// ---------------------------------------------------------------------------
// Kernel 1: 3x3 SAME conv, 256->128 channels, + bias.
// Block: 256 threads = 16x16 pixel tile x 32 output channels.
// Per-thread: 2x2 pixels x 8 ocs = 32 accumulators.
// Stages 2 input channels per barrier (18x18 patch + 32x9 weights each).
// ---------------------------------------------------------------------------
__global__ __launch_bounds__(256) void conv3x3_k(
    const float* __restrict__ feats, const float* __restrict__ cw,
    const float* __restrict__ cb, float* __restrict__ x)
{
    __shared__ float patch[2][18 * 21];   // stride 21 to spread banks
    __shared__ float wt[2][32 * 9];

    const int tid  = threadIdx.x;
    const int bx   = blockIdx.x;          // B*64 spatial tiles
    const int b    = bx >> 6;
    const int tile = bx & 63;
    const int ty0  = (tile >> 3) << 4;
    const int tx0  = (tile & 7) << 4;
    const int oc_base = blockIdx.y << 5;  // 4 groups of 32 ocs

    const int pos = tid & 63;
    const int wv  = tid >> 6;             // wave id -> oc sub-group (broadcast weights)
    const int px  = (pos & 7) << 1;
    const int py  = (pos >> 3) << 1;

    float acc[8][4];
#pragma unroll
    for (int o = 0; o < 8; ++o)
#pragma unroll
        for (int p = 0; p < 4; ++p) acc[o][p] = 0.f;

    for (int c = 0; c < INC; c += 2) {
        // stage patches (2 channels, 18x18 each, zero-padded at borders)
        for (int idx = tid; idx < 2 * 324; idx += 256) {
            int ch = idx >= 324;
            int r  = idx - ch * 324;
            int i = r / 18, j = r - i * 18;
            int gy = ty0 + i - 1, gx = tx0 + j - 1;
            float v = 0.f;
            if ((unsigned)gy < (unsigned)Hn && (unsigned)gx < (unsigned)Wn)
                v = feats[(((size_t)b * INC + c + ch) * Hn + gy) * Wn + gx];
            patch[ch][i * 21 + j] = v;
        }
        // stage weights (2 channels x 32 ocs x 9 taps)
        for (int idx = tid; idx < 2 * 288; idx += 256) {
            int ch = idx >= 288;
            int r  = idx - ch * 288;
            int k = r / 9, tap = r - k * 9;
            wt[ch][r] = cw[((size_t)(oc_base + k)) * (INC * 9) + (c + ch) * 9 + tap];
        }
        __syncthreads();

#pragma unroll
        for (int ch = 0; ch < 2; ++ch) {
            float pv[4][4];
#pragma unroll
            for (int i = 0; i < 4; ++i)
#pragma unroll
                for (int j = 0; j < 4; ++j)
                    pv[i][j] = patch[ch][(py + i) * 21 + px + j];
#pragma unroll
            for (int o = 0; o < 8; ++o) {
                const float* wo = &wt[ch][(wv * 8 + o) * 9];
                const float w0 = wo[0], w1 = wo[1], w2 = wo[2];
                const float w3 = wo[3], w4 = wo[4], w5 = wo[5];
                const float w6 = wo[6], w7 = wo[7], w8 = wo[8];
#pragma unroll
                for (int ii = 0; ii < 2; ++ii)
#pragma unroll
                    for (int jj = 0; jj < 2; ++jj) {
                        float s = acc[o][ii * 2 + jj];
                        s += w0 * pv[ii + 0][jj + 0]; s += w1 * pv[ii + 0][jj + 1]; s += w2 * pv[ii + 0][jj + 2];
                        s += w3 * pv[ii + 1][jj + 0]; s += w4 * pv[ii + 1][jj + 1]; s += w5 * pv[ii + 1][jj + 2];
                        s += w6 * pv[ii + 2][jj + 0]; s += w7 * pv[ii + 2][jj + 1]; s += w8 * pv[ii + 2][jj + 2];
                        acc[o][ii * 2 + jj] = s;
                    }
            }
        }
        __syncthreads();
    }

#pragma unroll
    for (int o = 0; o < 8; ++o) {
        int oc = oc_base + wv * 8 + o;
        float bias = cb[oc];
#pragma unroll
        for (int ii = 0; ii < 2; ++ii)
#pragma unroll
            for (int jj = 0; jj < 2; ++jj) {
                int gy = ty0 + py + ii, gx = tx0 + px + jj;
                x[(((size_t)b * KQn + oc) * Hn + gy) * Wn + gx] = acc[o][ii * 2 + jj] + bias;
            }
    }
}

// ---------------------------------------------------------------------------
// Kernel 2: keys + queries 1x1 GEMM, fused; writes PIXEL-MAJOR (B, HW, 128)
// so the gather kernel reads contiguous 512B rows.
// Block: 64 pixels x 256 outputs (128 keys + 128 queries). Thread: 4 px x 16 outs.
// ---------------------------------------------------------------------------
__global__ __launch_bounds__(256) void kq_k(
    const float* __restrict__ x, const float* __restrict__ kw,
    const float* __restrict__ qw, const float* __restrict__ kb,
    const float* __restrict__ qb, float* __restrict__ kT, float* __restrict__ qT)
{
    __shared__ float xs[32 * 64];
    __shared__ float wbuf[256 * 33];      // stride 33: break bank aliasing

    const int tid = threadIdx.x;
    const int b   = blockIdx.x >> 8;      // 256 pixel-tiles per batch
    const int p0  = (blockIdx.x & 255) << 6;
    const int P0  = (tid & 15) << 2;
    const int O0  = (tid >> 4) << 4;

    float acc[16][4];
#pragma unroll
    for (int o = 0; o < 16; ++o)
#pragma unroll
        for (int p = 0; p < 4; ++p) acc[o][p] = 0.f;

    for (int c0 = 0; c0 < 128; c0 += 32) {
        for (int idx = tid; idx < 2048; idx += 256) {
            int cc = idx >> 6, p = idx & 63;
            xs[cc * 64 + p] = x[((size_t)b * KQn + c0 + cc) * HW + p0 + p];
        }
        for (int idx = tid; idx < 8192; idx += 256) {
            int out = idx >> 5, cc = idx & 31;
            float w = (out < 128) ? kw[out * 128 + c0 + cc]
                                  : qw[(out - 128) * 128 + c0 + cc];
            wbuf[out * 33 + cc] = w;
        }
        __syncthreads();

#pragma unroll 4
        for (int cc = 0; cc < 32; ++cc) {
            float xv[4];
#pragma unroll
            for (int j = 0; j < 4; ++j) xv[j] = xs[cc * 64 + P0 + j];
#pragma unroll
            for (int o = 0; o < 16; ++o) {
                float w = wbuf[(O0 + o) * 33 + cc];
#pragma unroll
                for (int j = 0; j < 4; ++j) acc[o][j] += w * xv[j];
            }
        }
        __syncthreads();
    }

    const bool isK = (O0 < 128);
    const float* bias = isK ? kb : qb;
    float* dst = isK ? kT : qT;
    const int ob = isK ? O0 : O0 - 128;
#pragma unroll
    for (int p = 0; p < 4; ++p) {
        int gp = p0 + P0 + p;
#pragma unroll
        for (int og = 0; og < 4; ++og) {
            float4 v;
            v.x = acc[og * 4 + 0][p] + bias[ob + og * 4 + 0];
            v.y = acc[og * 4 + 1][p] + bias[ob + og * 4 + 1];
            v.z = acc[og * 4 + 2][p] + bias[ob + og * 4 + 2];
            v.w = acc[og * 4 + 3][p] + bias[ob + og * 4 + 3];
            *(float4*)&dst[((size_t)b * HW + gp) * 128 + ob + og * 4] = v;
        }
    }
}

// ---------------------------------------------------------------------------
// Kernel 3: s x s average pool on pixel-major (B, HW, 128) -> (B, np, 128)
// ---------------------------------------------------------------------------
__global__ __launch_bounds__(256) void pool_k(
    const float* __restrict__ src, float* __restrict__ dst,
    int s, int pw, int np)
{
    const int tid = threadIdx.x;
    const int nb8 = np >> 3;
    const int b   = blockIdx.x / nb8;
    const int ppb = (blockIdx.x - b * nb8) << 3;
    const int pp  = ppb + (tid >> 5);
    const int c4  = (tid & 31) << 2;
    const int ppy = pp / pw, ppx = pp - ppy * pw;

    float4 acc = {0.f, 0.f, 0.f, 0.f};
    for (int sy = 0; sy < s; ++sy)
        for (int sx = 0; sx < s; ++sx) {
            int sp = (ppy * s + sy) * Wn + ppx * s + sx;
            const float4 v = *(const float4*)&src[((size_t)b * HW + sp) * 128 + c4];
            acc.x += v.x; acc.y += v.y; acc.z += v.z; acc.w += v.w;
        }
    const float inv = 1.f / (float)(s * s);
    acc.x *= inv; acc.y *= inv; acc.z *= inv; acc.w *= inv;
    *(float4*)&dst[((size_t)b * np + pp) * 128 + c4] = acc;
}

// ---------------------------------------------------------------------------
// Kernel 4: gathered dot products. Block: 8 q-rows x 32 samples.
// q rows staged in LDS; k rows gathered (contiguous 512B each).
// ---------------------------------------------------------------------------
__global__ __launch_bounds__(256) void gdot_k(
    const float* __restrict__ qT, const float* __restrict__ kT,
    const int* __restrict__ inds, float* __restrict__ out,
    int n, int out_off)
{
    __shared__ float qs[8][128];
    const int tid = threadIdx.x;
    const int nb8 = n >> 3;
    const int b   = blockIdx.x / nb8;
    const int nb  = (blockIdx.x - b * nb8) << 3;

    for (int idx = tid; idx < 1024; idx += 256) {
        int r = idx >> 7, cc = idx & 127;
        qs[r][cc] = qT[((size_t)b * n + nb + r) * 128 + cc];
    }
    __syncthreads();

    const int r  = tid >> 5, si = tid & 31;
    const int nid = nb + r;
    const int ind = inds[((size_t)b * n + nid) * 32 + si];
    const float4* kr = (const float4*)&kT[((size_t)b * n + ind) * 128];
    const float4* qr = (const float4*)&qs[r][0];
    float acc = 0.f;
#pragma unroll
    for (int i = 0; i < 32; ++i) {
        float4 kv = kr[i], qv = qr[i];
        acc += qv.x * kv.x + qv.y * kv.y + qv.z * kv.z + qv.w * kv.w;
    }
    out[((size_t)b * NTOT + out_off + nid) * 32 + si] = acc * SCALE;
}

// ---------------------------------------------------------------------------
extern "C" void kernel_launch(void* const* d_in, const int* in_sizes, int n_in,
                              void* d_out, int out_size, void* d_ws, size_t ws_size,
                              hipStream_t stream)
{
    const float* feats = (const float*)d_in[0];
    const float* cw    = (const float*)d_in[1];
    const float* cb    = (const float*)d_in[2];
    const float* kw    = (const float*)d_in[3];
    const float* kb    = (const float*)d_in[4];
    const float* qw    = (const float*)d_in[5];
    const float* qb    = (const float*)d_in[6];
    const int*   i2    = (const int*)d_in[7];
    const int*   i3    = (const int*)d_in[8];
    const int*   i4    = (const int*)d_in[9];
    float* out = (float*)d_out;

    // workspace layout (floats): x | kT1 | qT1 | kT2 | qT2 | kT3 | qT3  (~61 MB)
    float* x   = (float*)d_ws;
    float* kT1 = x   + (size_t)B_ * KQn * HW;
    float* qT1 = kT1 + (size_t)B_ * HW * 128;
    float* kT2 = qT1 + (size_t)B_ * HW * 128;
    float* qT2 = kT2 + (size_t)B_ * 4096 * 128;
    float* kT3 = qT2 + (size_t)B_ * 4096 * 128;
    float* qT3 = kT3 + (size_t)B_ * 1024 * 128;

    conv3x3_k<<<dim3(B_ * 64, 4), 256, 0, stream>>>(feats, cw, cb, x);
    kq_k<<<dim3(B_ * 256), 256, 0, stream>>>(x, kw, qw, kb, qb, kT1, qT1);

    pool_k<<<dim3(B_ * 512), 256, 0, stream>>>(kT1, kT2, 2, 64, 4096);
    pool_k<<<dim3(B_ * 512), 256, 0, stream>>>(qT1, qT2, 2, 64, 4096);
    pool_k<<<dim3(B_ * 128), 256, 0, stream>>>(kT1, kT3, 4, 32, 1024);
    pool_k<<<dim3(B_ * 128), 256, 0, stream>>>(qT1, qT3, 4, 32, 1024);

    gdot_k<<<dim3(B_ * 2048), 256, 0, stream>>>(qT1, kT1, i2, out, 16384, 0);
    gdot_k<<<dim3(B_ * 512),  256, 0, stream>>>(qT2, kT2, i3, out, 4096, 16384);
    gdot_k<<<dim3(B_ * 128),  256, 0, stream>>>(qT3, kT3, i4, out, 1024, 20480);
}

// Round 2
// 291.956 us; speedup vs baseline: 2.1842x; 2.1842x over previous
//
#include <hip/hip_runtime.h>
#include <cstddef>
#include <cstdint>

typedef __attribute__((ext_vector_type(8))) short short8;
typedef __attribute__((ext_vector_type(4))) float f32x4;

namespace {
constexpr int B_   = 2;
constexpr int HW   = 16384;
constexpr int NTOT = 21504;
constexpr float SCALE = 0.088388347648318447f;  // 128^-0.5
}

__device__ __forceinline__ unsigned short f2bf(float f) {
    unsigned u = __builtin_bit_cast(unsigned, f);
    u += 0x7fffu + ((u >> 16) & 1u);
    return (unsigned short)(u >> 16);
}
__device__ __forceinline__ float bf2f(unsigned short h) {
    return __builtin_bit_cast(float, (unsigned)h << 16);
}
__device__ __forceinline__ float blo(unsigned u) {
    return __builtin_bit_cast(float, u << 16);
}
__device__ __forceinline__ float bhi(unsigned u) {
    return __builtin_bit_cast(float, u & 0xffff0000u);
}

// ---------------------------------------------------------------------------
// prep_w: pack combined weights ckw = key_w@conv_w, cqw = query_w@conv_w into
// MFMA-B-fragment order: wp[chunk8][tap9][nfrag16][lane64][i8] bf16, where
// oc = nfrag*16 + (lane&15) (nfrag 0-7 key, 8-15 query), ch = chunk*32 +
// (lane>>4)*8 + i. 576 blocks x 4 (c,tap) pairs each.
// ---------------------------------------------------------------------------
__global__ __launch_bounds__(256) void prep_w_k(
    const float* __restrict__ cw, const float* __restrict__ kw,
    const float* __restrict__ qw, unsigned short* __restrict__ wp)
{
    __shared__ float cvec[128][4];
    const int tid = threadIdx.x;
    const int g = blockIdx.x;
    for (int idx = tid; idx < 512; idx += 256) {
        int j = idx >> 2, q = idx & 3;
        int pair = (g << 2) + q;
        int c = pair / 9, tap = pair - c * 9;
        cvec[j][q] = cw[j * 2304 + c * 9 + tap];
    }
    __syncthreads();
    const int oc = tid & 127, isQ = tid >> 7;
    const float* wrow = (isQ ? qw : kw) + oc * 128;
    float acc0 = 0.f, acc1 = 0.f, acc2 = 0.f, acc3 = 0.f;
    for (int j = 0; j < 128; ++j) {
        float wv = wrow[j];
        acc0 += wv * cvec[j][0]; acc1 += wv * cvec[j][1];
        acc2 += wv * cvec[j][2]; acc3 += wv * cvec[j][3];
    }
    float accs[4] = {acc0, acc1, acc2, acc3};
#pragma unroll
    for (int q = 0; q < 4; ++q) {
        int pair = (g << 2) + q;
        int c = pair / 9, tap = pair - c * 9;
        int chunk = c >> 5, kg = (c >> 3) & 3, i = c & 7;
        int nf = (isQ << 3) + (oc >> 4);
        int lane = (kg << 4) + (oc & 15);
        wp[((size_t)(((chunk * 9 + tap) << 4) + nf) << 9) + (lane << 3) + i] = f2bf(accs[q]);
    }
}

// combined bias: key_w@conv_b + key_b (and query analog) -> bias[256] f32
__global__ __launch_bounds__(256) void prep_bias_k(
    const float* __restrict__ cb, const float* __restrict__ kw,
    const float* __restrict__ qw, const float* __restrict__ kb,
    const float* __restrict__ qb, float* __restrict__ bias)
{
    __shared__ float cbv[128];
    const int tid = threadIdx.x;
    if (tid < 128) cbv[tid] = cb[tid];
    __syncthreads();
    const int oc = tid & 127, isQ = tid >> 7;
    const float* wrow = (isQ ? qw : kw) + oc * 128;
    float a = isQ ? qb[oc] : kb[oc];
    for (int j = 0; j < 128; ++j) a += wrow[j] * cbv[j];
    bias[tid] = a;
}

// ---------------------------------------------------------------------------
// conv_kq_k: fused 3x3 conv (256ch) -> keys/queries (128+128) via bf16 MFMA.
// Grid: (512 pixel-tiles of 8x8, 2 oc-halves). Block 256 thr = 4 waves, each
// wave = 32 px (2 mfrags) x 64 oc (4 nfrags). K-loop: 8 chunks of 32 input ch,
// 9 taps each as one 16x16x32 MFMA K-step. Input patch (10x10 px x 32 ch bf16,
// 80B pixel stride) staged in LDS with inline fp32->bf16 convert; weights
// loaded straight from the prepacked L2-resident wp.
// ---------------------------------------------------------------------------
__global__ __launch_bounds__(256, 4) void conv_kq_k(
    const float* __restrict__ feats, const unsigned short* __restrict__ wp,
    const float* __restrict__ kqbias, unsigned short* __restrict__ kT,
    unsigned short* __restrict__ qT)
{
    __shared__ __align__(16) unsigned char patch[100 * 80];
    const int tid = threadIdx.x;
    const int b = blockIdx.x >> 8;
    const int tile = blockIdx.x & 255;
    const int ty0 = (tile >> 4) << 3, tx0 = (tile & 15) << 3;
    const int by = blockIdx.y;           // 0 = keys, 1 = queries
    const int w = tid >> 6, lane = tid & 63;
    const int p = lane & 15, kg = lane >> 4;
    const int prow = ((w >> 1) << 2) + (p >> 3);
    const int pcol = p & 7;
    const int nfb = (by << 3) + ((w & 1) << 2);
    const int kg16 = kg << 4;

    // chunk-invariant staging descriptors (static-indexed after unroll)
    int ldsoff[13], goff[13];
#pragma unroll
    for (int i = 0; i < 13; ++i) {
        int idx = tid + (i << 8);
        if (idx < 3200) {
            int c = idx / 100, pl = idx - c * 100;
            int py = pl / 10, px = pl - py * 10;
            int gy = ty0 + py - 1, gx = tx0 + px - 1;
            ldsoff[i] = pl * 80 + c * 2;
            goff[i] = ((unsigned)gy < 128u && (unsigned)gx < 128u)
                        ? (c << 14) + (gy << 7) + gx : -1;
        } else { ldsoff[i] = -1; goff[i] = -1; }
    }

    f32x4 acc[2][4];
#pragma unroll
    for (int m = 0; m < 2; ++m)
#pragma unroll
        for (int n = 0; n < 4; ++n) acc[m][n] = (f32x4){0.f, 0.f, 0.f, 0.f};

    for (int chunk = 0; chunk < 8; ++chunk) {
        const float* fb = feats + ((size_t)(b * 256 + chunk * 32) << 14);
#pragma unroll
        for (int i = 0; i < 13; ++i) {
            if (ldsoff[i] >= 0) {
                float v = 0.f;
                if (goff[i] >= 0) v = fb[goff[i]];
                *(unsigned short*)(patch + ldsoff[i]) = f2bf(v);
            }
        }
        __syncthreads();

        const unsigned short* wpc = wp + (size_t)chunk * 73728;
#pragma unroll
        for (int dy = 0; dy < 3; ++dy)
#pragma unroll
        for (int dx = 0; dx < 3; ++dx) {
            const int tap = dy * 3 + dx;
            short8 af[2];
#pragma unroll
            for (int m = 0; m < 2; ++m) {
                int pl = (prow + 2 * m + dy) * 10 + pcol + dx;
                af[m] = *(const short8*)(patch + pl * 80 + kg16);
            }
            const unsigned short* wpt = wpc + tap * 8192 + lane * 8;
#pragma unroll
            for (int n = 0; n < 4; ++n) {
                short8 bv = *(const short8*)(wpt + (nfb + n) * 512);
#pragma unroll
                for (int m = 0; m < 2; ++m)
                    acc[m][n] = __builtin_amdgcn_mfma_f32_16x16x32_bf16(
                        af[m], bv, acc[m][n], 0, 0, 0);
            }
        }
        __syncthreads();
    }

    unsigned short* dst = by ? qT : kT;
    const int ocl = ((w & 1) << 6) + (lane & 15);
#pragma unroll
    for (int n = 0; n < 4; ++n) {
        const float bias = kqbias[(by << 7) + ocl + (n << 4)];
#pragma unroll
        for (int m = 0; m < 2; ++m)
#pragma unroll
            for (int r = 0; r < 4; ++r) {
                int row = (kg << 2) + r;
                int py = ((w >> 1) << 2) + 2 * m + (row >> 3);
                int px = row & 7;
                int gp = ((ty0 + py) << 7) + tx0 + px;
                dst[(((size_t)b << 14) + gp) * 128 + ocl + (n << 4)] =
                    f2bf(acc[m][n][r] + bias);
            }
    }
}

// ---------------------------------------------------------------------------
// pool: s x s average on pixel-major bf16 (B,HW,128) -> (B,np,128)
// ---------------------------------------------------------------------------
__global__ __launch_bounds__(256) void pool_k(
    const unsigned short* __restrict__ src, unsigned short* __restrict__ dst,
    int s, int pwshift, int np)
{
    const int tid = threadIdx.x;
    const int b = blockIdx.y;
    const int pp = (blockIdx.x << 3) + (tid >> 5);
    const int c4 = (tid & 31) << 2;
    const int ppy = pp >> pwshift, ppx = pp & ((1 << pwshift) - 1);
    float a0 = 0.f, a1 = 0.f, a2 = 0.f, a3 = 0.f;
    for (int sy = 0; sy < s; ++sy)
        for (int sx = 0; sx < s; ++sx) {
            int sp = ((ppy * s + sy) << 7) + ppx * s + sx;
            ushort4 v = *(const ushort4*)(src + (((size_t)b << 14) + sp) * 128 + c4);
            a0 += bf2f(v.x); a1 += bf2f(v.y); a2 += bf2f(v.z); a3 += bf2f(v.w);
        }
    const float inv = 1.f / (float)(s * s);
    ushort4 o;
    o.x = f2bf(a0 * inv); o.y = f2bf(a1 * inv);
    o.z = f2bf(a2 * inv); o.w = f2bf(a3 * inv);
    *(ushort4*)(dst + ((size_t)b * np + pp) * 128 + c4) = o;
}

// ---------------------------------------------------------------------------
// gdot: gathered 128-dot per (pixel, sample). Block = 8 q-rows x 32 samples.
// q staged f32 in LDS; k rows gathered as bf16 uint4 (L2/L3-resident).
// ---------------------------------------------------------------------------
__global__ __launch_bounds__(256) void gdot_k(
    const unsigned short* __restrict__ qT, const unsigned short* __restrict__ kT,
    const int* __restrict__ inds, float* __restrict__ out, int n, int out_off)
{
    __shared__ float qs[8][128];
    const int tid = threadIdx.x;
    const int b = blockIdx.y;
    const int nb = blockIdx.x << 3;
    for (int idx = tid; idx < 1024; idx += 256) {
        int r = idx >> 7, cc = idx & 127;
        qs[r][cc] = bf2f(qT[((size_t)b * n + nb + r) * 128 + cc]);
    }
    __syncthreads();
    const int r = tid >> 5, si = tid & 31;
    const int nid = nb + r;
    const int ind = inds[((size_t)b * n + nid) * 32 + si];
    const uint4* kr = (const uint4*)(kT + ((size_t)b * n + ind) * 128);
    const float* qp = qs[r];
    float acc = 0.f;
#pragma unroll
    for (int i = 0; i < 16; ++i) {
        uint4 kv = kr[i];
        const float* q8 = qp + (i << 3);
        acc += q8[0] * blo(kv.x) + q8[1] * bhi(kv.x)
             + q8[2] * blo(kv.y) + q8[3] * bhi(kv.y)
             + q8[4] * blo(kv.z) + q8[5] * bhi(kv.z)
             + q8[6] * blo(kv.w) + q8[7] * bhi(kv.w);
    }
    out[((size_t)b * NTOT + out_off + nid) * 32 + si] = acc * SCALE;
}

// ---------------------------------------------------------------------------
extern "C" void kernel_launch(void* const* d_in, const int* in_sizes, int n_in,
                              void* d_out, int out_size, void* d_ws, size_t ws_size,
                              hipStream_t stream)
{
    const float* feats = (const float*)d_in[0];
    const float* cw    = (const float*)d_in[1];
    const float* cb    = (const float*)d_in[2];
    const float* kw    = (const float*)d_in[3];
    const float* kb    = (const float*)d_in[4];
    const float* qw    = (const float*)d_in[5];
    const float* qb    = (const float*)d_in[6];
    const int*   i2    = (const int*)d_in[7];
    const int*   i3    = (const int*)d_in[8];
    const int*   i4    = (const int*)d_in[9];
    float* out = (float*)d_out;

    char* ws = (char*)d_ws;
    unsigned short* wp   = (unsigned short*)ws;                 // 1,179,648 B
    float*          bias = (float*)(ws + 1179648);              // 1,024 B
    unsigned short* kT1  = (unsigned short*)(ws + 1180672);     // 8,388,608 B
    unsigned short* qT1  = kT1 + 4194304;                       // 8,388,608 B
    unsigned short* kT2  = qT1 + 4194304;                       // 2,097,152 B
    unsigned short* qT2  = kT2 + 1048576;                       // 2,097,152 B
    unsigned short* kT3  = qT2 + 1048576;                       //   524,288 B
    unsigned short* qT3  = kT3 + 262144;                        //   524,288 B

    prep_w_k<<<dim3(576), 256, 0, stream>>>(cw, kw, qw, wp);
    prep_bias_k<<<dim3(1), 256, 0, stream>>>(cb, kw, qw, kb, qb, bias);
    conv_kq_k<<<dim3(512, 2), 256, 0, stream>>>(feats, wp, bias, kT1, qT1);

    pool_k<<<dim3(512, 2), 256, 0, stream>>>(kT1, kT2, 2, 6, 4096);
    pool_k<<<dim3(512, 2), 256, 0, stream>>>(qT1, qT2, 2, 6, 4096);
    pool_k<<<dim3(128, 2), 256, 0, stream>>>(kT1, kT3, 4, 5, 1024);
    pool_k<<<dim3(128, 2), 256, 0, stream>>>(qT1, qT3, 4, 5, 1024);

    gdot_k<<<dim3(2048, 2), 256, 0, stream>>>(qT1, kT1, i2, out, 16384, 0);
    gdot_k<<<dim3(512, 2),  256, 0, stream>>>(qT2, kT2, i3, out, 4096, 16384);
    gdot_k<<<dim3(128, 2),  256, 0, stream>>>(qT3, kT3, i4, out, 1024, 20480);
}

// Round 3
// 232.471 us; speedup vs baseline: 2.7431x; 1.2559x over previous
//
#include <hip/hip_runtime.h>
#include <cstddef>
#include <cstdint>

typedef __attribute__((ext_vector_type(8))) short short8;
typedef __attribute__((ext_vector_type(4))) float f32x4;

namespace {
constexpr int B_   = 2;
constexpr int HW   = 16384;
constexpr int NTOT = 21504;
constexpr float SCALE = 0.088388347648318447f;  // 128^-0.5
}

__device__ __forceinline__ unsigned short f2bf(float f) {
    unsigned u = __builtin_bit_cast(unsigned, f);
    u += 0x7fffu + ((u >> 16) & 1u);
    return (unsigned short)(u >> 16);
}
__device__ __forceinline__ float bf2f(unsigned short h) {
    return __builtin_bit_cast(float, (unsigned)h << 16);
}
__device__ __forceinline__ float blo(unsigned u) {
    return __builtin_bit_cast(float, u << 16);
}
__device__ __forceinline__ float bhi(unsigned u) {
    return __builtin_bit_cast(float, u & 0xffff0000u);
}
__device__ __forceinline__ void gload_lds16(const void* g, void* l) {
    __builtin_amdgcn_global_load_lds(
        (const __attribute__((address_space(1))) void*)g,
        (__attribute__((address_space(3))) void*)l, 16, 0, 0);
}

// ---------------------------------------------------------------------------
// zb_k: zero the 1-px border of fpm (B,130,130,256) bf16. 1032 blocks x 64.
// ---------------------------------------------------------------------------
__global__ __launch_bounds__(64) void zb_k(unsigned short* __restrict__ fpm)
{
    int bid = blockIdx.x;
    int b = bid >= 516;
    int i = bid - b * 516;
    int yy, xx;
    if (i < 130)      { yy = 0;       xx = i; }
    else if (i < 260) { yy = 129;     xx = i - 130; }
    else if (i < 388) { yy = i - 259; xx = 0; }      // rows 1..128
    else              { yy = i - 387; xx = 129; }
    ((unsigned long long*)fpm)[((size_t)(b * 130 + yy) * 130 + xx) * 64 + threadIdx.x] = 0ull;
}

// ---------------------------------------------------------------------------
// t_k: NCHW fp32 -> pixel-major bf16 (B,130,130,256) interior. 512 blocks:
// (b, y, xhalf). LDS transpose, c-major rows of 72 shorts.
// ---------------------------------------------------------------------------
__global__ __launch_bounds__(256) void t_k(
    const float* __restrict__ feats, unsigned short* __restrict__ fpm)
{
    __shared__ unsigned short ls[256 * 72];   // 36,864 B
    const int tid = threadIdx.x;
    const int b    = blockIdx.x >> 8;
    const int rem  = blockIdx.x & 255;
    const int y    = rem >> 1;
    const int gx0  = (rem & 1) << 6;

    const int cs = tid >> 4, x0 = (tid & 15) << 2;
#pragma unroll
    for (int j = 0; j < 16; ++j) {
        int c = (j << 4) + cs;
        float4 v = *(const float4*)&feats[(((size_t)b * 256 + c) << 14) + (y << 7) + gx0 + x0];
        uint2 pk;
        pk.x = (unsigned)f2bf(v.x) | ((unsigned)f2bf(v.y) << 16);
        pk.y = (unsigned)f2bf(v.z) | ((unsigned)f2bf(v.w) << 16);
        *(uint2*)&ls[c * 72 + x0] = pk;
    }
    __syncthreads();

    const int x = tid >> 2, q = tid & 3;
    unsigned short* orow = fpm +
        (((size_t)(b * 130 + y + 1) * 130) + 1 + gx0 + x) * 256 + (q << 6);
#pragma unroll
    for (int u = 0; u < 8; ++u) {
        int c0 = (q << 6) + (u << 3);
        unsigned w0 = (unsigned)ls[(c0 + 0) * 72 + x] | ((unsigned)ls[(c0 + 1) * 72 + x] << 16);
        unsigned w1 = (unsigned)ls[(c0 + 2) * 72 + x] | ((unsigned)ls[(c0 + 3) * 72 + x] << 16);
        unsigned w2 = (unsigned)ls[(c0 + 4) * 72 + x] | ((unsigned)ls[(c0 + 5) * 72 + x] << 16);
        unsigned w3 = (unsigned)ls[(c0 + 6) * 72 + x] | ((unsigned)ls[(c0 + 7) * 72 + x] << 16);
        uint4 o; o.x = w0; o.y = w1; o.z = w2; o.w = w3;
        *(uint4*)(orow + (u << 3)) = o;
    }
}

// ---------------------------------------------------------------------------
// prep_w: combined weights (key_w@conv_w, query_w@conv_w) packed as MFMA B
// fragments: wp[(kstep*16 + nf)*512 + lane*8 + i] bf16, kstep = chunk*9+tap,
// oc = nf*16 + (lane&15) (nf 0-7 key, 8-15 query), ch = chunk*32+(lane>>4)*8+i.
// ---------------------------------------------------------------------------
__global__ __launch_bounds__(256) void prep_w_k(
    const float* __restrict__ cw, const float* __restrict__ kw,
    const float* __restrict__ qw, unsigned short* __restrict__ wp)
{
    __shared__ float cvec[128][4];
    const int tid = threadIdx.x;
    const int g = blockIdx.x;
    for (int idx = tid; idx < 512; idx += 256) {
        int j = idx >> 2, q = idx & 3;
        int pair = (g << 2) + q;
        int c = pair / 9, tap = pair - c * 9;
        cvec[j][q] = cw[j * 2304 + c * 9 + tap];
    }
    __syncthreads();
    const int oc = tid & 127, isQ = tid >> 7;
    const float* wrow = (isQ ? qw : kw) + oc * 128;
    float acc0 = 0.f, acc1 = 0.f, acc2 = 0.f, acc3 = 0.f;
    for (int j = 0; j < 128; ++j) {
        float wv = wrow[j];
        acc0 += wv * cvec[j][0]; acc1 += wv * cvec[j][1];
        acc2 += wv * cvec[j][2]; acc3 += wv * cvec[j][3];
    }
    float accs[4] = {acc0, acc1, acc2, acc3};
#pragma unroll
    for (int q = 0; q < 4; ++q) {
        int pair = (g << 2) + q;
        int c = pair / 9, tap = pair - c * 9;
        int chunk = c >> 5, kg = (c >> 3) & 3, i = c & 7;
        int nf = (isQ << 3) + (oc >> 4);
        int lane = (kg << 4) + (oc & 15);
        wp[((size_t)(((chunk * 9 + tap) << 4) + nf) << 9) + (lane << 3) + i] = f2bf(accs[q]);
    }
}

__global__ __launch_bounds__(256) void prep_bias_k(
    const float* __restrict__ cb, const float* __restrict__ kw,
    const float* __restrict__ qw, const float* __restrict__ kb,
    const float* __restrict__ qb, float* __restrict__ bias)
{
    __shared__ float cbv[128];
    const int tid = threadIdx.x;
    if (tid < 128) cbv[tid] = cb[tid];
    __syncthreads();
    const int oc = tid & 127, isQ = tid >> 7;
    const float* wrow = (isQ ? qw : kw) + oc * 128;
    float a = isQ ? qb[oc] : kb[oc];
    for (int j = 0; j < 128; ++j) a += wrow[j] * cbv[j];
    bias[tid] = a;
}

// ---------------------------------------------------------------------------
// conv2_k: fused 3x3 conv -> 256 outputs (128 key + 128 query), bf16 MFMA.
// 512 blocks = (b, 16x16 tiles of 8x8 px). 4 waves; wave w owns n-frags
// w*4..w*4+3 and all 4 m-frags (acc 4x4 f32x4 = 64 VGPR). A staged per 32-ch
// chunk via global_load_lds (double-buffered, 1 barrier/chunk); B fragments
// loaded global->VGPR from L2-resident wp. 72 K-steps of 16x16x32.
// ---------------------------------------------------------------------------
__global__ __launch_bounds__(256, 2) void conv2_k(
    const unsigned short* __restrict__ fpm, const unsigned short* __restrict__ wp,
    const float* __restrict__ kqbias, unsigned short* __restrict__ kT,
    unsigned short* __restrict__ qT)
{
    __shared__ __align__(16) unsigned char abuf[2][7168];
    const int tid = threadIdx.x;
    const int w = tid >> 6, lane = tid & 63;
    const int b = blockIdx.x >> 8, tile = blockIdx.x & 255;
    const int ty0 = (tile >> 4) << 3, tx0 = (tile & 15) << 3;
    const int r = lane & 15, g = lane >> 4;

    // staging geometry: instr i covers pixels pl0 = 16i + (lane>>2), 16B each
    const int sp_sub = lane >> 2, sp_o = (lane & 3) << 4;
    const int pbase = (((r >> 3) * 10) + (r & 7)) * 64 + (g << 4);
    const unsigned char* wpB = (const unsigned char*)wp + ((w << 2) << 10) + (lane << 4);

    f32x4 acc[4][4];
#pragma unroll
    for (int mi = 0; mi < 4; ++mi)
#pragma unroll
        for (int ni = 0; ni < 4; ++ni) acc[mi][ni] = (f32x4){0.f, 0.f, 0.f, 0.f};

    auto stage = [&](int chunk, int buf) {
#pragma unroll
        for (int k = 0; k < 2; ++k) {
            int i = w + (k << 2);
            if (i < 7) {
                int pl0 = (i << 4) + sp_sub;
                int y = (pl0 * 6554) >> 16;
                int x = pl0 - y * 10;
                const unsigned char* src = (const unsigned char*)fpm +
                    (((size_t)((b * 130 + ty0 + y) * 130 + tx0 + x)) << 9) +
                    (chunk << 6) + sp_o;
                gload_lds16(src, &abuf[buf][i << 10]);
            }
        }
    };

    stage(0, 0);
    __syncthreads();

    for (int chunk = 0; chunk < 8; ++chunk) {
        const unsigned char* ab = abuf[chunk & 1];
        if (chunk < 7) stage(chunk + 1, (chunk + 1) & 1);
        const unsigned char* wbase = wpB + (size_t)chunk * 147456;
#pragma unroll
        for (int tap = 0; tap < 9; ++tap) {
            const int dy = tap / 3, dx = tap % 3;
            short8 bf[4];
#pragma unroll
            for (int ni = 0; ni < 4; ++ni)
                bf[ni] = *(const short8*)(wbase + tap * 16384 + (ni << 10));
            short8 af[4];
#pragma unroll
            for (int mi = 0; mi < 4; ++mi)
                af[mi] = *(const short8*)(ab + pbase + (((2 * mi + dy) * 10 + dx) << 6));
#pragma unroll
            for (int mi = 0; mi < 4; ++mi)
#pragma unroll
                for (int ni = 0; ni < 4; ++ni)
                    acc[mi][ni] = __builtin_amdgcn_mfma_f32_16x16x32_bf16(
                        af[mi], bf[ni], acc[mi][ni], 0, 0, 0);
        }
        __syncthreads();
    }

    const int col = lane & 15;
    const int mrow0 = g << 2;
#pragma unroll
    for (int ni = 0; ni < 4; ++ni) {
        int nf = (w << 2) + ni;
        unsigned short* dst = (nf < 8) ? kT : qT;
        int oc = ((nf & 7) << 4) + col;
        float bias = kqbias[(nf < 8 ? 0 : 128) + oc];
#pragma unroll
        for (int mi = 0; mi < 4; ++mi)
#pragma unroll
            for (int reg = 0; reg < 4; ++reg) {
                int m = mrow0 + reg;
                int ly = 2 * mi + (m >> 3), lx = m & 7;
                int gp = ((ty0 + ly) << 7) + tx0 + lx;
                dst[(((size_t)b << 14) + gp) * 128 + oc] = f2bf(acc[mi][ni][reg] + bias);
            }
    }
}

// ---------------------------------------------------------------------------
// pool: s x s average on pixel-major bf16 (B,HW,128) -> (B,np,128)
// ---------------------------------------------------------------------------
__global__ __launch_bounds__(256) void pool_k(
    const unsigned short* __restrict__ src, unsigned short* __restrict__ dst,
    int s, int pwshift, int np)
{
    const int tid = threadIdx.x;
    const int b = blockIdx.y;
    const int pp = (blockIdx.x << 3) + (tid >> 5);
    const int c4 = (tid & 31) << 2;
    const int ppy = pp >> pwshift, ppx = pp & ((1 << pwshift) - 1);
    float a0 = 0.f, a1 = 0.f, a2 = 0.f, a3 = 0.f;
    for (int sy = 0; sy < s; ++sy)
        for (int sx = 0; sx < s; ++sx) {
            int sp = ((ppy * s + sy) << 7) + ppx * s + sx;
            ushort4 v = *(const ushort4*)(src + (((size_t)b << 14) + sp) * 128 + c4);
            a0 += bf2f(v.x); a1 += bf2f(v.y); a2 += bf2f(v.z); a3 += bf2f(v.w);
        }
    const float inv = 1.f / (float)(s * s);
    ushort4 o;
    o.x = f2bf(a0 * inv); o.y = f2bf(a1 * inv);
    o.z = f2bf(a2 * inv); o.w = f2bf(a3 * inv);
    *(ushort4*)(dst + ((size_t)b * np + pp) * 128 + c4) = o;
}

// ---------------------------------------------------------------------------
// gdot: gathered 128-dot per (pixel, sample). Block = 8 q-rows x 32 samples.
// ---------------------------------------------------------------------------
__global__ __launch_bounds__(256) void gdot_k(
    const unsigned short* __restrict__ qT, const unsigned short* __restrict__ kT,
    const int* __restrict__ inds, float* __restrict__ out, int n, int out_off)
{
    __shared__ float qs[8][128];
    const int tid = threadIdx.x;
    const int b = blockIdx.y;
    const int nb = blockIdx.x << 3;
    for (int idx = tid; idx < 1024; idx += 256) {
        int r = idx >> 7, cc = idx & 127;
        qs[r][cc] = bf2f(qT[((size_t)b * n + nb + r) * 128 + cc]);
    }
    __syncthreads();
    const int r = tid >> 5, si = tid & 31;
    const int nid = nb + r;
    const int ind = inds[((size_t)b * n + nid) * 32 + si];
    const uint4* kr = (const uint4*)(kT + ((size_t)b * n + ind) * 128);
    const float* qp = qs[r];
    float acc = 0.f;
#pragma unroll
    for (int i = 0; i < 16; ++i) {
        uint4 kv = kr[i];
        const float* q8 = qp + (i << 3);
        acc += q8[0] * blo(kv.x) + q8[1] * bhi(kv.x)
             + q8[2] * blo(kv.y) + q8[3] * bhi(kv.y)
             + q8[4] * blo(kv.z) + q8[5] * bhi(kv.z)
             + q8[6] * blo(kv.w) + q8[7] * bhi(kv.w);
    }
    out[((size_t)b * NTOT + out_off + nid) * 32 + si] = acc * SCALE;
}

// ---------------------------------------------------------------------------
extern "C" void kernel_launch(void* const* d_in, const int* in_sizes, int n_in,
                              void* d_out, int out_size, void* d_ws, size_t ws_size,
                              hipStream_t stream)
{
    const float* feats = (const float*)d_in[0];
    const float* cw    = (const float*)d_in[1];
    const float* cb    = (const float*)d_in[2];
    const float* kw    = (const float*)d_in[3];
    const float* kb    = (const float*)d_in[4];
    const float* qw    = (const float*)d_in[5];
    const float* qb    = (const float*)d_in[6];
    const int*   i2    = (const int*)d_in[7];
    const int*   i3    = (const int*)d_in[8];
    const int*   i4    = (const int*)d_in[9];
    float* out = (float*)d_out;

    char* ws = (char*)d_ws;
    unsigned short* wp   = (unsigned short*)ws;                    // 1,179,648 B
    float*          bias = (float*)(ws + 1179648);                 //     1,024 B
    unsigned short* fpm  = (unsigned short*)(ws + 1180672);        // 17,443,840 B (incl. tail slack)
    unsigned short* kT1  = (unsigned short*)(ws + 18624512);       // 8,388,608 B
    unsigned short* qT1  = kT1 + 4194304;
    unsigned short* kT2  = qT1 + 4194304;                          // 2,097,152 B
    unsigned short* qT2  = kT2 + 1048576;
    unsigned short* kT3  = qT2 + 1048576;                          //   524,288 B
    unsigned short* qT3  = kT3 + 262144;

    zb_k<<<dim3(1032), 64, 0, stream>>>(fpm);
    t_k<<<dim3(512), 256, 0, stream>>>(feats, fpm);
    prep_w_k<<<dim3(576), 256, 0, stream>>>(cw, kw, qw, wp);
    prep_bias_k<<<dim3(1), 256, 0, stream>>>(cb, kw, qw, kb, qb, bias);
    conv2_k<<<dim3(512), 256, 0, stream>>>(fpm, wp, bias, kT1, qT1);

    pool_k<<<dim3(512, 2), 256, 0, stream>>>(kT1, kT2, 2, 6, 4096);
    pool_k<<<dim3(512, 2), 256, 0, stream>>>(qT1, qT2, 2, 6, 4096);
    pool_k<<<dim3(128, 2), 256, 0, stream>>>(kT1, kT3, 4, 5, 1024);
    pool_k<<<dim3(128, 2), 256, 0, stream>>>(qT1, qT3, 4, 5, 1024);

    gdot_k<<<dim3(2048, 2), 256, 0, stream>>>(qT1, kT1, i2, out, 16384, 0);
    gdot_k<<<dim3(512, 2),  256, 0, stream>>>(qT2, kT2, i3, out, 4096, 16384);
    gdot_k<<<dim3(128, 2),  256, 0, stream>>>(qT3, kT3, i4, out, 1024, 20480);
}

// Round 4
// 212.238 us; speedup vs baseline: 3.0046x; 1.0953x over previous
//
#include <hip/hip_runtime.h>
#include <cstddef>
#include <cstdint>

typedef __attribute__((ext_vector_type(8))) short short8;
typedef __attribute__((ext_vector_type(4))) float f32x4;

namespace {
constexpr int B_   = 2;
constexpr int HW   = 16384;
constexpr int NTOT = 21504;
constexpr float SCALE = 0.088388347648318447f;  // 128^-0.5
}

__device__ __forceinline__ unsigned short f2bf(float f) {
    unsigned u = __builtin_bit_cast(unsigned, f);
    u += 0x7fffu + ((u >> 16) & 1u);
    return (unsigned short)(u >> 16);
}
__device__ __forceinline__ float bf2f(unsigned short h) {
    return __builtin_bit_cast(float, (unsigned)h << 16);
}
__device__ __forceinline__ float blo(unsigned u) {
    return __builtin_bit_cast(float, u << 16);
}
__device__ __forceinline__ float bhi(unsigned u) {
    return __builtin_bit_cast(float, u & 0xffff0000u);
}
__device__ __forceinline__ void gload_lds16(const void* g, void* l) {
    __builtin_amdgcn_global_load_lds(
        (const __attribute__((address_space(1))) void*)g,
        (__attribute__((address_space(3))) void*)l, 16, 0, 0);
}

// ---------------------------------------------------------------------------
// zb_k: zero the 1-px border of fpm (B,130,130,256) bf16.
// ---------------------------------------------------------------------------
__global__ __launch_bounds__(64) void zb_k(unsigned short* __restrict__ fpm)
{
    int bid = blockIdx.x;
    int b = bid >= 516;
    int i = bid - b * 516;
    int yy, xx;
    if (i < 130)      { yy = 0;       xx = i; }
    else if (i < 260) { yy = 129;     xx = i - 130; }
    else if (i < 388) { yy = i - 259; xx = 0; }
    else              { yy = i - 387; xx = 129; }
    ((unsigned long long*)fpm)[((size_t)(b * 130 + yy) * 130 + xx) * 64 + threadIdx.x] = 0ull;
}

// ---------------------------------------------------------------------------
// t_k: NCHW fp32 -> pixel-major bf16 (B,130,130,256) interior.
// ---------------------------------------------------------------------------
__global__ __launch_bounds__(256) void t_k(
    const float* __restrict__ feats, unsigned short* __restrict__ fpm)
{
    __shared__ unsigned short ls[256 * 72];
    const int tid = threadIdx.x;
    const int b    = blockIdx.x >> 8;
    const int rem  = blockIdx.x & 255;
    const int y    = rem >> 1;
    const int gx0  = (rem & 1) << 6;

    const int cs = tid >> 4, x0 = (tid & 15) << 2;
#pragma unroll
    for (int j = 0; j < 16; ++j) {
        int c = (j << 4) + cs;
        float4 v = *(const float4*)&feats[(((size_t)b * 256 + c) << 14) + (y << 7) + gx0 + x0];
        uint2 pk;
        pk.x = (unsigned)f2bf(v.x) | ((unsigned)f2bf(v.y) << 16);
        pk.y = (unsigned)f2bf(v.z) | ((unsigned)f2bf(v.w) << 16);
        *(uint2*)&ls[c * 72 + x0] = pk;
    }
    __syncthreads();

    const int x = tid >> 2, q = tid & 3;
    unsigned short* orow = fpm +
        (((size_t)(b * 130 + y + 1) * 130) + 1 + gx0 + x) * 256 + (q << 6);
#pragma unroll
    for (int u = 0; u < 8; ++u) {
        int c0 = (q << 6) + (u << 3);
        unsigned w0 = (unsigned)ls[(c0 + 0) * 72 + x] | ((unsigned)ls[(c0 + 1) * 72 + x] << 16);
        unsigned w1 = (unsigned)ls[(c0 + 2) * 72 + x] | ((unsigned)ls[(c0 + 3) * 72 + x] << 16);
        unsigned w2 = (unsigned)ls[(c0 + 4) * 72 + x] | ((unsigned)ls[(c0 + 5) * 72 + x] << 16);
        unsigned w3 = (unsigned)ls[(c0 + 6) * 72 + x] | ((unsigned)ls[(c0 + 7) * 72 + x] << 16);
        uint4 o; o.x = w0; o.y = w1; o.z = w2; o.w = w3;
        *(uint4*)(orow + (u << 3)) = o;
    }
}

// ---------------------------------------------------------------------------
// prep_w / prep_bias: fold key/query 1x1 into conv weights, pack B-fragments.
// ---------------------------------------------------------------------------
__global__ __launch_bounds__(256) void prep_w_k(
    const float* __restrict__ cw, const float* __restrict__ kw,
    const float* __restrict__ qw, unsigned short* __restrict__ wp)
{
    __shared__ float cvec[128][4];
    const int tid = threadIdx.x;
    const int g = blockIdx.x;
    for (int idx = tid; idx < 512; idx += 256) {
        int j = idx >> 2, q = idx & 3;
        int pair = (g << 2) + q;
        int c = pair / 9, tap = pair - c * 9;
        cvec[j][q] = cw[j * 2304 + c * 9 + tap];
    }
    __syncthreads();
    const int oc = tid & 127, isQ = tid >> 7;
    const float* wrow = (isQ ? qw : kw) + oc * 128;
    float acc0 = 0.f, acc1 = 0.f, acc2 = 0.f, acc3 = 0.f;
    for (int j = 0; j < 128; ++j) {
        float wv = wrow[j];
        acc0 += wv * cvec[j][0]; acc1 += wv * cvec[j][1];
        acc2 += wv * cvec[j][2]; acc3 += wv * cvec[j][3];
    }
    float accs[4] = {acc0, acc1, acc2, acc3};
#pragma unroll
    for (int q = 0; q < 4; ++q) {
        int pair = (g << 2) + q;
        int c = pair / 9, tap = pair - c * 9;
        int chunk = c >> 5, kg = (c >> 3) & 3, i = c & 7;
        int nf = (isQ << 3) + (oc >> 4);
        int lane = (kg << 4) + (oc & 15);
        wp[((size_t)(((chunk * 9 + tap) << 4) + nf) << 9) + (lane << 3) + i] = f2bf(accs[q]);
    }
}

__global__ __launch_bounds__(256) void prep_bias_k(
    const float* __restrict__ cb, const float* __restrict__ kw,
    const float* __restrict__ qw, const float* __restrict__ kb,
    const float* __restrict__ qb, float* __restrict__ bias)
{
    __shared__ float cbv[128];
    const int tid = threadIdx.x;
    if (tid < 128) cbv[tid] = cb[tid];
    __syncthreads();
    const int oc = tid & 127, isQ = tid >> 7;
    const float* wrow = (isQ ? qw : kw) + oc * 128;
    float a = isQ ? qb[oc] : kb[oc];
    for (int j = 0; j < 128; ++j) a += wrow[j] * cbv[j];
    bias[tid] = a;
}

// ---------------------------------------------------------------------------
// conv2_k: fused 3x3 conv -> 256 outputs, bf16 MFMA, register-dbuf B prefetch.
// ---------------------------------------------------------------------------
__global__ __launch_bounds__(256, 2) void conv2_k(
    const unsigned short* __restrict__ fpm, const unsigned short* __restrict__ wp,
    const float* __restrict__ kqbias, unsigned short* __restrict__ kT,
    unsigned short* __restrict__ qT)
{
    __shared__ __align__(16) unsigned char abuf[2][7168];
    const int tid = threadIdx.x;
    const int w = tid >> 6, lane = tid & 63;
    const int raw = blockIdx.x;
    const int bid = ((raw & 7) << 6) + (raw >> 3);   // XCD-chunked swizzle (512 = 8*64)
    const int b = bid >> 8, tile = bid & 255;
    const int ty0 = (tile >> 4) << 3, tx0 = (tile & 15) << 3;
    const int r = lane & 15, g = lane >> 4;

    const int sp_sub = lane >> 2, sp_o = (lane & 3) << 4;
    const int pbase = (((r >> 3) * 10) + (r & 7)) * 64 + (g << 4);
    const unsigned char* wpB = (const unsigned char*)wp + ((w << 2) << 10) + (lane << 4);

    f32x4 acc[4][4];
#pragma unroll
    for (int mi = 0; mi < 4; ++mi)
#pragma unroll
        for (int ni = 0; ni < 4; ++ni) acc[mi][ni] = (f32x4){0.f, 0.f, 0.f, 0.f};

    auto stage = [&](int chunk, int buf) {
#pragma unroll
        for (int k = 0; k < 2; ++k) {
            int i = w + (k << 2);
            if (i < 7) {
                int pl0 = (i << 4) + sp_sub;
                int y = (pl0 * 6554) >> 16;
                int x = pl0 - y * 10;
                const unsigned char* src = (const unsigned char*)fpm +
                    (((size_t)((b * 130 + ty0 + y) * 130 + tx0 + x)) << 9) +
                    (chunk << 6) + sp_o;
                gload_lds16(src, &abuf[buf][i << 10]);
            }
        }
    };

    stage(0, 0);
    __syncthreads();

    for (int chunk = 0; chunk < 8; ++chunk) {
        const unsigned char* ab = abuf[chunk & 1];
        if (chunk < 7) stage(chunk + 1, (chunk + 1) & 1);
        const unsigned char* wbase = wpB + (size_t)chunk * 147456;

        short8 breg[2][4];
#pragma unroll
        for (int ni = 0; ni < 4; ++ni)
            breg[0][ni] = *(const short8*)(wbase + (ni << 10));

#pragma unroll
        for (int tap = 0; tap < 9; ++tap) {
            const int dy = tap / 3, dx = tap % 3;
            const int cur = tap & 1, nxt = cur ^ 1;
            if (tap < 8) {
#pragma unroll
                for (int ni = 0; ni < 4; ++ni)
                    breg[nxt][ni] = *(const short8*)(wbase + (tap + 1) * 16384 + (ni << 10));
            }
            short8 af[4];
#pragma unroll
            for (int mi = 0; mi < 4; ++mi)
                af[mi] = *(const short8*)(ab + pbase + (((2 * mi + dy) * 10 + dx) << 6));
#pragma unroll
            for (int mi = 0; mi < 4; ++mi)
#pragma unroll
                for (int ni = 0; ni < 4; ++ni)
                    acc[mi][ni] = __builtin_amdgcn_mfma_f32_16x16x32_bf16(
                        af[mi], breg[cur][ni], acc[mi][ni], 0, 0, 0);
        }
        __syncthreads();
    }

    const int col = lane & 15;
    const int mrow0 = g << 2;
#pragma unroll
    for (int ni = 0; ni < 4; ++ni) {
        int nf = (w << 2) + ni;
        unsigned short* dst = (nf < 8) ? kT : qT;
        int oc = ((nf & 7) << 4) + col;
        float bias = kqbias[(nf < 8 ? 0 : 128) + oc];
#pragma unroll
        for (int mi = 0; mi < 4; ++mi)
#pragma unroll
            for (int reg = 0; reg < 4; ++reg) {
                int m = mrow0 + reg;
                int ly = 2 * mi + (m >> 3), lx = m & 7;
                int gp = ((ty0 + ly) << 7) + tx0 + lx;
                dst[(((size_t)b << 14) + gp) * 128 + oc] = f2bf(acc[mi][ni][reg] + bias);
            }
    }
}

// ---------------------------------------------------------------------------
// pool_all_k: all 4 pooling jobs in one dispatch. 2560 blocks x 256 thr.
// ---------------------------------------------------------------------------
__global__ __launch_bounds__(256) void pool_all_k(
    const unsigned short* __restrict__ kT1, const unsigned short* __restrict__ qT1,
    unsigned short* __restrict__ kT2, unsigned short* __restrict__ qT2,
    unsigned short* __restrict__ kT3, unsigned short* __restrict__ qT3)
{
    const int bid = blockIdx.x;
    const unsigned short* src; unsigned short* dst;
    int s, pwshift, np, b, bx;
    if (bid < 2048) {
        int j = bid & 1023;
        src = (bid < 1024) ? kT1 : qT1; dst = (bid < 1024) ? kT2 : qT2;
        s = 2; pwshift = 6; np = 4096; b = j >> 9; bx = j & 511;
    } else {
        int j = (bid - 2048) & 255;
        src = (bid < 2304) ? kT1 : qT1; dst = (bid < 2304) ? kT3 : qT3;
        s = 4; pwshift = 5; np = 1024; b = j >> 7; bx = j & 127;
    }
    const int tid = threadIdx.x;
    const int pp = (bx << 3) + (tid >> 5);
    const int c4 = (tid & 31) << 2;
    const int ppy = pp >> pwshift, ppx = pp & ((1 << pwshift) - 1);
    float a0 = 0.f, a1 = 0.f, a2 = 0.f, a3 = 0.f;
    for (int sy = 0; sy < s; ++sy)
        for (int sx = 0; sx < s; ++sx) {
            int sp = ((ppy * s + sy) << 7) + ppx * s + sx;
            ushort4 v = *(const ushort4*)(src + (((size_t)b << 14) + sp) * 128 + c4);
            a0 += bf2f(v.x); a1 += bf2f(v.y); a2 += bf2f(v.z); a3 += bf2f(v.w);
        }
    const float inv = 1.f / (float)(s * s);
    ushort4 o;
    o.x = f2bf(a0 * inv); o.y = f2bf(a1 * inv);
    o.z = f2bf(a2 * inv); o.w = f2bf(a3 * inv);
    *(ushort4*)(dst + ((size_t)b * np + pp) * 128 + c4) = o;
}

// ---------------------------------------------------------------------------
// gdot_all_k: all 3 levels in one dispatch. 672 blocks x 512 thr (8 waves).
// Block = 8x8 pixel tile. Local samples (s<25) read from a 12x12 k-row window
// staged in LDS (XOR-swizzled, bank-balanced b128); 7 random samples from L2.
// Thread = (pixel, 16-channel slice); 8-lane shfl reduce per dot.
// ---------------------------------------------------------------------------
__global__ __launch_bounds__(512, 2) void gdot_all_k(
    const unsigned short* __restrict__ qT1, const unsigned short* __restrict__ kT1,
    const unsigned short* __restrict__ qT2, const unsigned short* __restrict__ kT2,
    const unsigned short* __restrict__ qT3, const unsigned short* __restrict__ kT3,
    const int* __restrict__ i2, const int* __restrict__ i3, const int* __restrict__ i4,
    float* __restrict__ out)
{
    __shared__ __align__(16) unsigned char kwin[144 * 256];   // 36,864 B

    const int raw = blockIdx.x;
    const int bid = (raw & 7) * 84 + (raw >> 3);              // 672 = 8*84, bijective

    const unsigned short *qT, *kT;
    const int* inds;
    int n, wshift, tpbsh, twsh, off;
    if (bid < 512) {
        qT = qT1; kT = kT1; inds = i2; n = 16384; wshift = 7; tpbsh = 8; twsh = 4; off = 0;
    } else if (bid < 640) {
        qT = qT2; kT = kT2; inds = i3; n = 4096;  wshift = 6; tpbsh = 6; twsh = 3; off = 16384;
    } else {
        qT = qT3; kT = kT3; inds = i4; n = 1024;  wshift = 5; tpbsh = 4; twsh = 2; off = 20480;
    }
    const int lb   = bid - ((bid < 512) ? 0 : (bid < 640) ? 512 : 640);
    const int b    = lb >> tpbsh;
    const int tile = lb & ((1 << tpbsh) - 1);
    const int ty0  = (tile >> twsh) << 3;
    const int tx0  = (tile & ((1 << twsh) - 1)) << 3;
    const int W    = 1 << wshift, Wm1 = W - 1;
    const int ry0  = ty0 - 2, cx0 = tx0 - 2;

    const int tid   = threadIdx.x;
    const int pxl   = tid >> 3;          // 0..63 local pixel
    const int slice = tid & 7;           // 16-channel slice
    const int py = pxl >> 3, px = pxl & 7;
    const int nid = ((ty0 + py) << wshift) + tx0 + px;

    // stage 12x12 window of k-rows (clamped), 16B chunks, XOR swizzle on word
    for (int idx = tid; idx < 2304; idx += 512) {
        int slot = idx >> 4, w16 = idx & 15;
        int sy = ry0 + slot / 12, sx = cx0 + slot % 12;
        sy = min(max(sy, 0), Wm1); sx = min(max(sx, 0), Wm1);
        uint4 v = *(const uint4*)(kT + ((size_t)(b * n + (sy << wshift) + sx) * 128) + (w16 << 3));
        *(uint4*)&kwin[slot * 256 + ((w16 ^ (slot & 7)) << 4)] = v;
    }

    // q slice -> 16 f32 registers
    float qr[16];
    {
        const uint4* qp = (const uint4*)(qT + ((size_t)(b * n + nid) * 128) + (slice << 4));
        uint4 q0 = qp[0], q1 = qp[1];
        qr[0] = blo(q0.x); qr[1] = bhi(q0.x); qr[2] = blo(q0.y); qr[3] = bhi(q0.y);
        qr[4] = blo(q0.z); qr[5] = bhi(q0.z); qr[6] = blo(q0.w); qr[7] = bhi(q0.w);
        qr[8] = blo(q1.x); qr[9] = bhi(q1.x); qr[10] = blo(q1.y); qr[11] = bhi(q1.y);
        qr[12] = blo(q1.z); qr[13] = bhi(q1.z); qr[14] = blo(q1.w); qr[15] = bhi(q1.w);
    }
    __syncthreads();

    const int* irow = inds + ((size_t)(b * n + nid) << 5);
    const int w2 = slice << 1;
    float* orow = out + (((size_t)b * NTOT + off + nid) << 5);

    for (int s = 0; s < 32; ++s) {
        int ind = irow[s];
        uint4 k0, k1;
        if (s < 25) {
            int iy = ind >> wshift, ix = ind & Wm1;
            int slot = (iy - ry0) * 12 + (ix - cx0);
            int sw = slot & 7;
            const unsigned char* base = kwin + slot * 256;
            k0 = *(const uint4*)(base + ((w2 ^ sw) << 4));
            k1 = *(const uint4*)(base + (((w2 + 1) ^ sw) << 4));
        } else {
            const uint4* kp = (const uint4*)(kT + ((size_t)(b * n + ind) * 128) + (slice << 4));
            k0 = kp[0]; k1 = kp[1];
        }
        float a = qr[0] * blo(k0.x) + qr[1] * bhi(k0.x)
                + qr[2] * blo(k0.y) + qr[3] * bhi(k0.y)
                + qr[4] * blo(k0.z) + qr[5] * bhi(k0.z)
                + qr[6] * blo(k0.w) + qr[7] * bhi(k0.w)
                + qr[8] * blo(k1.x) + qr[9] * bhi(k1.x)
                + qr[10] * blo(k1.y) + qr[11] * bhi(k1.y)
                + qr[12] * blo(k1.z) + qr[13] * bhi(k1.z)
                + qr[14] * blo(k1.w) + qr[15] * bhi(k1.w);
        a += __shfl_xor(a, 1);
        a += __shfl_xor(a, 2);
        a += __shfl_xor(a, 4);
        if (slice == 0) orow[s] = a * SCALE;
    }
}

// ---------------------------------------------------------------------------
extern "C" void kernel_launch(void* const* d_in, const int* in_sizes, int n_in,
                              void* d_out, int out_size, void* d_ws, size_t ws_size,
                              hipStream_t stream)
{
    const float* feats = (const float*)d_in[0];
    const float* cw    = (const float*)d_in[1];
    const float* cb    = (const float*)d_in[2];
    const float* kw    = (const float*)d_in[3];
    const float* kb    = (const float*)d_in[4];
    const float* qw    = (const float*)d_in[5];
    const float* qb    = (const float*)d_in[6];
    const int*   i2    = (const int*)d_in[7];
    const int*   i3    = (const int*)d_in[8];
    const int*   i4    = (const int*)d_in[9];
    float* out = (float*)d_out;

    char* ws = (char*)d_ws;
    unsigned short* wp   = (unsigned short*)ws;                 // 1,179,648 B
    float*          bias = (float*)(ws + 1179648);              //     1,024 B
    unsigned short* fpm  = (unsigned short*)(ws + 1180672);     // 17,305,600 B (+slack)
    unsigned short* kT1  = (unsigned short*)(ws + 18624512);    // 8,388,608 B
    unsigned short* qT1  = kT1 + 4194304;
    unsigned short* kT2  = qT1 + 4194304;                       // 2,097,152 B
    unsigned short* qT2  = kT2 + 1048576;
    unsigned short* kT3  = qT2 + 1048576;                       //   524,288 B
    unsigned short* qT3  = kT3 + 262144;

    zb_k<<<dim3(1032), 64, 0, stream>>>(fpm);
    t_k<<<dim3(512), 256, 0, stream>>>(feats, fpm);
    prep_w_k<<<dim3(576), 256, 0, stream>>>(cw, kw, qw, wp);
    prep_bias_k<<<dim3(1), 256, 0, stream>>>(cb, kw, qw, kb, qb, bias);
    conv2_k<<<dim3(512), 256, 0, stream>>>(fpm, wp, bias, kT1, qT1);
    pool_all_k<<<dim3(2560), 256, 0, stream>>>(kT1, qT1, kT2, qT2, kT3, qT3);
    gdot_all_k<<<dim3(672), 512, 0, stream>>>(qT1, kT1, qT2, kT2, qT3, kT3,
                                              i2, i3, i4, out);
}

// Round 5
// 186.909 us; speedup vs baseline: 3.4118x; 1.1355x over previous
//
#include <hip/hip_runtime.h>
#include <cstddef>
#include <cstdint>

typedef __attribute__((ext_vector_type(8))) short short8;
typedef __attribute__((ext_vector_type(4))) float f32x4;

namespace {
constexpr int B_   = 2;
constexpr int HW   = 16384;
constexpr int NTOT = 21504;
constexpr float SCALE = 0.088388347648318447f;  // 128^-0.5
}

__device__ __forceinline__ unsigned short f2bf(float f) {
    unsigned u = __builtin_bit_cast(unsigned, f);
    u += 0x7fffu + ((u >> 16) & 1u);
    return (unsigned short)(u >> 16);
}
__device__ __forceinline__ float bf2f(unsigned short h) {
    return __builtin_bit_cast(float, (unsigned)h << 16);
}
__device__ __forceinline__ float blo(unsigned u) {
    return __builtin_bit_cast(float, u << 16);
}
__device__ __forceinline__ float bhi(unsigned u) {
    return __builtin_bit_cast(float, u & 0xffff0000u);
}
__device__ __forceinline__ unsigned pk2(float a, float b) {
    return (unsigned)f2bf(a) | ((unsigned)f2bf(b) << 16);
}
__device__ __forceinline__ void gload_lds16(const void* g, void* l) {
    __builtin_amdgcn_global_load_lds(
        (const __attribute__((address_space(1))) void*)g,
        (__attribute__((address_space(3))) void*)l, 16, 0, 0);
}

// ---------------------------------------------------------------------------
// t2_k: NCHW fp32 -> pixel-major bf16 (B,130,130,256), borders zeroed.
// Grid (260, 2): blockIdx.x = y*2+xseg (y in 0..129), blockIdx.y = b.
// lane = x => every channel load is a coalesced 256B wave read. No LDS.
// ---------------------------------------------------------------------------
__global__ __launch_bounds__(256) void t2_k(
    const float* __restrict__ feats, unsigned short* __restrict__ fpm)
{
    const int tid = threadIdx.x;
    const int lane = tid & 63, cg = tid >> 6;
    const int y = blockIdx.x >> 1, xseg = blockIdx.x & 1;
    const int b = blockIdx.y;
    const int x = (xseg << 6) + lane;
    const bool inter = (y >= 1 && y <= 128);
    const float* src = feats + (((size_t)b * 256) << 14) + ((y - 1) << 7) + x;
    unsigned short* orow = fpm + ((size_t)(b * 130 + y) * 130 + 1 + x) * 256;

#pragma unroll
    for (int it = 0; it < 8; ++it) {
        const int c0 = (it << 5) + (cg << 3);
        uint4 v = {0u, 0u, 0u, 0u};
        if (inter) {
            float f0 = src[(size_t)(c0 + 0) << 14], f1 = src[(size_t)(c0 + 1) << 14];
            float f2 = src[(size_t)(c0 + 2) << 14], f3 = src[(size_t)(c0 + 3) << 14];
            float f4 = src[(size_t)(c0 + 4) << 14], f5 = src[(size_t)(c0 + 5) << 14];
            float f6 = src[(size_t)(c0 + 6) << 14], f7 = src[(size_t)(c0 + 7) << 14];
            v.x = pk2(f0, f1); v.y = pk2(f2, f3); v.z = pk2(f4, f5); v.w = pk2(f6, f7);
        }
        *(uint4*)(orow + c0) = v;
    }
    // side columns 0 and 129 (once per row)
    if (xseg == 0) {
        uint4 z = {0u, 0u, 0u, 0u};
        if (tid < 32)
            *(uint4*)(fpm + ((size_t)(b * 130 + y) * 130 + 0) * 256 + (tid << 3)) = z;
        else if (tid < 64)
            *(uint4*)(fpm + ((size_t)(b * 130 + y) * 130 + 129) * 256 + ((tid - 32) << 3)) = z;
    }
}

// ---------------------------------------------------------------------------
// prep_k: blocks 0..575 pack combined weights (key_w@conv_w, query_w@conv_w)
// into MFMA B-fragment order; block 576 computes the combined bias.
// ---------------------------------------------------------------------------
__global__ __launch_bounds__(256) void prep_k(
    const float* __restrict__ cw, const float* __restrict__ kw,
    const float* __restrict__ qw, const float* __restrict__ cb,
    const float* __restrict__ kb, const float* __restrict__ qb,
    unsigned short* __restrict__ wp, float* __restrict__ bias)
{
    const int tid = threadIdx.x;
    if (blockIdx.x == 576) {
        __shared__ float cbv[128];
        if (tid < 128) cbv[tid] = cb[tid];
        __syncthreads();
        const int oc = tid & 127, isQ = tid >> 7;
        const float* wrow = (isQ ? qw : kw) + oc * 128;
        float a = isQ ? qb[oc] : kb[oc];
        for (int j = 0; j < 128; ++j) a += wrow[j] * cbv[j];
        bias[tid] = a;
        return;
    }
    __shared__ float cvec[128][4];
    const int g = blockIdx.x;
    for (int idx = tid; idx < 512; idx += 256) {
        int j = idx >> 2, q = idx & 3;
        int pair = (g << 2) + q;
        int c = pair / 9, tap = pair - c * 9;
        cvec[j][q] = cw[j * 2304 + c * 9 + tap];
    }
    __syncthreads();
    const int oc = tid & 127, isQ = tid >> 7;
    const float* wrow = (isQ ? qw : kw) + oc * 128;
    float acc0 = 0.f, acc1 = 0.f, acc2 = 0.f, acc3 = 0.f;
    for (int j = 0; j < 128; ++j) {
        float wv = wrow[j];
        acc0 += wv * cvec[j][0]; acc1 += wv * cvec[j][1];
        acc2 += wv * cvec[j][2]; acc3 += wv * cvec[j][3];
    }
    float accs[4] = {acc0, acc1, acc2, acc3};
#pragma unroll
    for (int q = 0; q < 4; ++q) {
        int pair = (g << 2) + q;
        int c = pair / 9, tap = pair - c * 9;
        int chunk = c >> 5, kg = (c >> 3) & 3, i = c & 7;
        int nf = (isQ << 3) + (oc >> 4);
        int lane = (kg << 4) + (oc & 15);
        wp[((size_t)(((chunk * 9 + tap) << 4) + nf) << 9) + (lane << 3) + i] = f2bf(accs[q]);
    }
}

// ---------------------------------------------------------------------------
// conv3_k: fused 3x3 conv -> 256 outputs (key|query) via bf16 MFMA, with
// in-block epilogue: LDS obuf -> vectorized kT1/qT1 writes + pool2 + pool4.
// 512 blocks (b x 256 tiles of 8x8 px), 4 waves.
// ---------------------------------------------------------------------------
__global__ __launch_bounds__(256, 2) void conv3_k(
    const unsigned short* __restrict__ fpm, const unsigned short* __restrict__ wp,
    const float* __restrict__ kqbias, unsigned short* __restrict__ kT,
    unsigned short* __restrict__ qT, unsigned short* __restrict__ kT2,
    unsigned short* __restrict__ qT2, unsigned short* __restrict__ kT3,
    unsigned short* __restrict__ qT3)
{
    __shared__ __align__(16) unsigned char abuf[2][7168];
    __shared__ __align__(16) unsigned short obuf[64 * 264];   // stride 264 u16

    const int tid = threadIdx.x;
    const int w = tid >> 6, lane = tid & 63;
    const int bid = blockIdx.x;
    const int b = bid >> 8, tile = bid & 255;
    const int ty0 = (tile >> 4) << 3, tx0 = (tile & 15) << 3;
    const int r = lane & 15, g = lane >> 4;

    const int sp_sub = lane >> 2, sp_o = (lane & 3) << 4;
    const int pbase = (((r >> 3) * 10) + (r & 7)) * 64 + (g << 4);
    const unsigned char* wpB = (const unsigned char*)wp + ((w << 2) << 10) + (lane << 4);

    f32x4 acc[4][4];
#pragma unroll
    for (int mi = 0; mi < 4; ++mi)
#pragma unroll
        for (int ni = 0; ni < 4; ++ni) acc[mi][ni] = (f32x4){0.f, 0.f, 0.f, 0.f};

    auto stage = [&](int chunk, int buf) {
#pragma unroll
        for (int k = 0; k < 2; ++k) {
            int i = w + (k << 2);
            if (i < 7) {
                int pl0 = (i << 4) + sp_sub;
                int y = (pl0 * 6554) >> 16;
                int x = pl0 - y * 10;
                const unsigned char* src = (const unsigned char*)fpm +
                    (((size_t)((b * 130 + ty0 + y) * 130 + tx0 + x)) << 9) +
                    (chunk << 6) + sp_o;
                gload_lds16(src, &abuf[buf][i << 10]);
            }
        }
    };

    stage(0, 0);
    __syncthreads();

    for (int chunk = 0; chunk < 8; ++chunk) {
        const unsigned char* ab = abuf[chunk & 1];
        if (chunk < 7) stage(chunk + 1, (chunk + 1) & 1);
        const unsigned char* wbase = wpB + (size_t)chunk * 147456;
#pragma unroll
        for (int tap = 0; tap < 9; ++tap) {
            const int dy = tap / 3, dx = tap % 3;
            short8 bf[4];
#pragma unroll
            for (int ni = 0; ni < 4; ++ni)
                bf[ni] = *(const short8*)(wbase + tap * 16384 + (ni << 10));
            short8 af[4];
#pragma unroll
            for (int mi = 0; mi < 4; ++mi)
                af[mi] = *(const short8*)(ab + pbase + (((2 * mi + dy) * 10 + dx) << 6));
#pragma unroll
            for (int mi = 0; mi < 4; ++mi)
#pragma unroll
                for (int ni = 0; ni < 4; ++ni)
                    acc[mi][ni] = __builtin_amdgcn_mfma_f32_16x16x32_bf16(
                        af[mi], bf[ni], acc[mi][ni], 0, 0, 0);
        }
        __syncthreads();
    }

    // epilogue: acc -> obuf (bf16, +bias); oc256 = nf*16+col
    const int col = lane & 15;
    const int mrow0 = g << 2;
#pragma unroll
    for (int ni = 0; ni < 4; ++ni) {
        const int nf = (w << 2) + ni;
        const float bv = kqbias[(nf << 4) + col];
#pragma unroll
        for (int mi = 0; mi < 4; ++mi)
#pragma unroll
            for (int reg = 0; reg < 4; ++reg) {
                int m = mrow0 + reg;
                int pxl = ((2 * mi + (m >> 3)) << 3) + (m & 7);
                obuf[pxl * 264 + (nf << 4) + col] = f2bf(acc[mi][ni][reg] + bv);
            }
    }
    __syncthreads();

    // kT1/qT1: thread = (px, 64-oc quarter), 8x uint4
    {
        const int px = tid >> 2, q = tid & 3;
        const int gp = ((ty0 + (px >> 3)) << 7) + tx0 + (px & 7);
        const unsigned short* srow = obuf + px * 264 + (q << 6);
        unsigned short* dp = (q < 2)
            ? kT + ((((size_t)b << 14) + gp) << 7) + (q << 6)
            : qT + ((((size_t)b << 14) + gp) << 7) + ((q - 2) << 6);
#pragma unroll
        for (int j = 0; j < 8; ++j)
            *(uint4*)(dp + (j << 3)) = *(const uint4*)(srow + (j << 3));
    }

    // pool2: 16 pooled px x 16 oc-groups
    {
        const int pp = tid >> 4, ocg = tid & 15, oc0 = ocg << 4;
        const int py2 = pp >> 2, px2 = pp & 3;
        const int gp2 = (((ty0 >> 1) + py2) << 6) + (tx0 >> 1) + px2;
        unsigned short* dp = (oc0 < 128)
            ? kT2 + (((size_t)b * 4096 + gp2) << 7) + oc0
            : qT2 + (((size_t)b * 4096 + gp2) << 7) + (oc0 - 128);
#pragma unroll
        for (int h = 0; h < 2; ++h) {
            float s0=0,s1=0,s2=0,s3=0,s4=0,s5=0,s6=0,s7=0;
#pragma unroll
            for (int dy = 0; dy < 2; ++dy)
#pragma unroll
                for (int dx = 0; dx < 2; ++dx) {
                    int pxl = (((py2 << 1) + dy) << 3) + (px2 << 1) + dx;
                    uint4 v = *(const uint4*)(obuf + pxl * 264 + oc0 + (h << 3));
                    s0 += blo(v.x); s1 += bhi(v.x); s2 += blo(v.y); s3 += bhi(v.y);
                    s4 += blo(v.z); s5 += bhi(v.z); s6 += blo(v.w); s7 += bhi(v.w);
                }
            uint4 o;
            o.x = pk2(s0 * 0.25f, s1 * 0.25f); o.y = pk2(s2 * 0.25f, s3 * 0.25f);
            o.z = pk2(s4 * 0.25f, s5 * 0.25f); o.w = pk2(s6 * 0.25f, s7 * 0.25f);
            *(uint4*)(dp + (h << 3)) = o;
        }
    }

    // pool4: 4 pooled px x 16 oc-groups (threads 0..63)
    if (tid < 64) {
        const int pp = tid >> 4, ocg = tid & 15, oc0 = ocg << 4;
        const int py4 = pp >> 1, px4 = pp & 1;
        const int gp4 = (((ty0 >> 2) + py4) << 5) + (tx0 >> 2) + px4;
        unsigned short* dp = (oc0 < 128)
            ? kT3 + (((size_t)b * 1024 + gp4) << 7) + oc0
            : qT3 + (((size_t)b * 1024 + gp4) << 7) + (oc0 - 128);
#pragma unroll
        for (int h = 0; h < 2; ++h) {
            float s0=0,s1=0,s2=0,s3=0,s4=0,s5=0,s6=0,s7=0;
#pragma unroll
            for (int dy = 0; dy < 4; ++dy)
#pragma unroll
                for (int dx = 0; dx < 4; ++dx) {
                    int pxl = (((py4 << 2) + dy) << 3) + (px4 << 2) + dx;
                    uint4 v = *(const uint4*)(obuf + pxl * 264 + oc0 + (h << 3));
                    s0 += blo(v.x); s1 += bhi(v.x); s2 += blo(v.y); s3 += bhi(v.y);
                    s4 += blo(v.z); s5 += bhi(v.z); s6 += blo(v.w); s7 += bhi(v.w);
                }
            const float f = 0.0625f;
            uint4 o;
            o.x = pk2(s0 * f, s1 * f); o.y = pk2(s2 * f, s3 * f);
            o.z = pk2(s4 * f, s5 * f); o.w = pk2(s6 * f, s7 * f);
            *(uint4*)(dp + (h << 3)) = o;
        }
    }
}

// ---------------------------------------------------------------------------
// gdot_all_k: all 3 levels, 672 blocks x 512 thr. Index preload (8x int4),
// 7 random k-rows prefetched to regs, locals from XOR-swizzled LDS window,
// results buffered -> one coalesced float4 store per lane.
// ---------------------------------------------------------------------------
__global__ __launch_bounds__(512) void gdot_all_k(
    const unsigned short* __restrict__ qT1, const unsigned short* __restrict__ kT1,
    const unsigned short* __restrict__ qT2, const unsigned short* __restrict__ kT2,
    const unsigned short* __restrict__ qT3, const unsigned short* __restrict__ kT3,
    const int* __restrict__ i2, const int* __restrict__ i3, const int* __restrict__ i4,
    float* __restrict__ out)
{
    __shared__ __align__(16) unsigned char kwin[144 * 256];   // 36,864 B

    const int raw = blockIdx.x;
    const int bid = (raw & 7) * 84 + (raw >> 3);              // 672 = 8*84, bijective

    const unsigned short *qT, *kT;
    const int* inds;
    int n, wshift, tpbsh, twsh, off;
    if (bid < 512) {
        qT = qT1; kT = kT1; inds = i2; n = 16384; wshift = 7; tpbsh = 8; twsh = 4; off = 0;
    } else if (bid < 640) {
        qT = qT2; kT = kT2; inds = i3; n = 4096;  wshift = 6; tpbsh = 6; twsh = 3; off = 16384;
    } else {
        qT = qT3; kT = kT3; inds = i4; n = 1024;  wshift = 5; tpbsh = 4; twsh = 2; off = 20480;
    }
    const int lb   = bid - ((bid < 512) ? 0 : (bid < 640) ? 512 : 640);
    const int b    = lb >> tpbsh;
    const int tile = lb & ((1 << tpbsh) - 1);
    const int ty0  = (tile >> twsh) << 3;
    const int tx0  = (tile & ((1 << twsh) - 1)) << 3;
    const int W    = 1 << wshift, Wm1 = W - 1;
    const int ry0  = ty0 - 2, cx0 = tx0 - 2;

    const int tid   = threadIdx.x;
    const int pxl   = tid >> 3;
    const int slice = tid & 7;
    const int py = pxl >> 3, px = pxl & 7;
    const int nid = ((ty0 + py) << wshift) + tx0 + px;

    for (int idx = tid; idx < 2304; idx += 512) {
        int slot = idx >> 4, w16 = idx & 15;
        int sy = ry0 + slot / 12, sx = cx0 + slot % 12;
        sy = min(max(sy, 0), Wm1); sx = min(max(sx, 0), Wm1);
        uint4 v = *(const uint4*)(kT + ((size_t)(b * n + (sy << wshift) + sx) * 128) + (w16 << 3));
        *(uint4*)&kwin[slot * 256 + ((w16 ^ (slot & 7)) << 4)] = v;
    }

    float qr[16];
    {
        const uint4* qp = (const uint4*)(qT + ((size_t)(b * n + nid) * 128) + (slice << 4));
        uint4 q0 = qp[0], q1 = qp[1];
        qr[0] = blo(q0.x); qr[1] = bhi(q0.x); qr[2] = blo(q0.y); qr[3] = bhi(q0.y);
        qr[4] = blo(q0.z); qr[5] = bhi(q0.z); qr[6] = blo(q0.w); qr[7] = bhi(q0.w);
        qr[8] = blo(q1.x); qr[9] = bhi(q1.x); qr[10] = blo(q1.y); qr[11] = bhi(q1.y);
        qr[12] = blo(q1.z); qr[13] = bhi(q1.z); qr[14] = blo(q1.w); qr[15] = bhi(q1.w);
    }
    __syncthreads();

    const int* irow = inds + ((size_t)(b * n + nid) << 5);
    int ia[32];
    {
        const int4* ip = (const int4*)irow;
#pragma unroll
        for (int j = 0; j < 8; ++j) {
            int4 v = ip[j];
            ia[4 * j] = v.x; ia[4 * j + 1] = v.y; ia[4 * j + 2] = v.z; ia[4 * j + 3] = v.w;
        }
    }

    uint4 rk0[7], rk1[7];
#pragma unroll
    for (int rr = 0; rr < 7; ++rr) {
        const uint4* kp = (const uint4*)(kT + (((size_t)(b * n + ia[25 + rr])) << 7) + (slice << 4));
        rk0[rr] = kp[0]; rk1[rr] = kp[1];
    }

    const int w2 = slice << 1;
    float res4[4] = {0.f, 0.f, 0.f, 0.f};
    float* orow = out + (((size_t)b * NTOT + off + nid) << 5);

#pragma unroll
    for (int s = 0; s < 32; ++s) {
        uint4 k0, k1;
        if (s < 25) {
            int ind = ia[s];
            int iy = ind >> wshift, ix = ind & Wm1;
            int slot = (iy - ry0) * 12 + (ix - cx0);
            int sw = slot & 7;
            const unsigned char* base2 = kwin + slot * 256;
            k0 = *(const uint4*)(base2 + ((w2 ^ sw) << 4));
            k1 = *(const uint4*)(base2 + (((w2 + 1) ^ sw) << 4));
        } else {
            k0 = rk0[s - 25]; k1 = rk1[s - 25];
        }
        float a = qr[0] * blo(k0.x) + qr[1] * bhi(k0.x)
                + qr[2] * blo(k0.y) + qr[3] * bhi(k0.y)
                + qr[4] * blo(k0.z) + qr[5] * bhi(k0.z)
                + qr[6] * blo(k0.w) + qr[7] * bhi(k0.w)
                + qr[8] * blo(k1.x) + qr[9] * bhi(k1.x)
                + qr[10] * blo(k1.y) + qr[11] * bhi(k1.y)
                + qr[12] * blo(k1.z) + qr[13] * bhi(k1.z)
                + qr[14] * blo(k1.w) + qr[15] * bhi(k1.w);
        a += __shfl_xor(a, 1);
        a += __shfl_xor(a, 2);
        a += __shfl_xor(a, 4);
        if ((s >> 2) == slice) res4[s & 3] = a * SCALE;
    }
    *(float4*)(orow + (slice << 2)) = *(const float4*)res4;
}

// ---------------------------------------------------------------------------
extern "C" void kernel_launch(void* const* d_in, const int* in_sizes, int n_in,
                              void* d_out, int out_size, void* d_ws, size_t ws_size,
                              hipStream_t stream)
{
    const float* feats = (const float*)d_in[0];
    const float* cw    = (const float*)d_in[1];
    const float* cb    = (const float*)d_in[2];
    const float* kw    = (const float*)d_in[3];
    const float* kb    = (const float*)d_in[4];
    const float* qw    = (const float*)d_in[5];
    const float* qb    = (const float*)d_in[6];
    const int*   i2    = (const int*)d_in[7];
    const int*   i3    = (const int*)d_in[8];
    const int*   i4    = (const int*)d_in[9];
    float* out = (float*)d_out;

    char* ws = (char*)d_ws;
    unsigned short* wp   = (unsigned short*)ws;                 // 1,179,648 B
    float*          bias = (float*)(ws + 1179648);              //     1,024 B
    unsigned short* fpm  = (unsigned short*)(ws + 1180672);     // 17,305,600 B (+slack)
    unsigned short* kT1  = (unsigned short*)(ws + 18624512);    // 8,388,608 B
    unsigned short* qT1  = kT1 + 4194304;
    unsigned short* kT2  = qT1 + 4194304;                       // 2,097,152 B
    unsigned short* qT2  = kT2 + 1048576;
    unsigned short* kT3  = qT2 + 1048576;                       //   524,288 B
    unsigned short* qT3  = kT3 + 262144;

    t2_k<<<dim3(260, 2), 256, 0, stream>>>(feats, fpm);
    prep_k<<<dim3(577), 256, 0, stream>>>(cw, kw, qw, cb, kb, qb, wp, bias);
    conv3_k<<<dim3(512), 256, 0, stream>>>(fpm, wp, bias, kT1, qT1,
                                           kT2, qT2, kT3, qT3);
    gdot_all_k<<<dim3(672), 512, 0, stream>>>(qT1, kT1, qT2, kT2, qT3, kT3,
                                              i2, i3, i4, out);
}

// Round 6
// 178.095 us; speedup vs baseline: 3.5806x; 1.0495x over previous
//
#include <hip/hip_runtime.h>
#include <cstddef>
#include <cstdint>

typedef __attribute__((ext_vector_type(8))) short short8;
typedef __attribute__((ext_vector_type(4))) float f32x4;

namespace {
constexpr int B_   = 2;
constexpr int HW   = 16384;
constexpr int NTOT = 21504;
constexpr float SCALE = 0.088388347648318447f;  // 128^-0.5
}

__device__ __forceinline__ unsigned short f2bf(float f) {
    unsigned u = __builtin_bit_cast(unsigned, f);
    u += 0x7fffu + ((u >> 16) & 1u);
    return (unsigned short)(u >> 16);
}
__device__ __forceinline__ float bf2f(unsigned short h) {
    return __builtin_bit_cast(float, (unsigned)h << 16);
}
__device__ __forceinline__ float blo(unsigned u) {
    return __builtin_bit_cast(float, u << 16);
}
__device__ __forceinline__ float bhi(unsigned u) {
    return __builtin_bit_cast(float, u & 0xffff0000u);
}
__device__ __forceinline__ unsigned pk2(float a, float b) {
    return (unsigned)f2bf(a) | ((unsigned)f2bf(b) << 16);
}
__device__ __forceinline__ void gload_lds16(const void* g, void* l) {
    __builtin_amdgcn_global_load_lds(
        (const __attribute__((address_space(1))) void*)g,
        (__attribute__((address_space(3))) void*)l, 16, 0, 0);
}

// counted-vmcnt barriers (T4): keep the just-issued stage (2 loads/wave) in
// flight across the barrier; drain only at the last prefetch.
#define KBAR2() asm volatile("s_waitcnt vmcnt(2)\ns_barrier" ::: "memory")
#define KBAR0() asm volatile("s_waitcnt vmcnt(0)\ns_barrier" ::: "memory")

// ---------------------------------------------------------------------------
// tp_k: one dispatch, three jobs by block range.
//   blocks 0..519    : NCHW fp32 -> pixel-major bf16 (B,130,130,256), borders 0
//   blocks 520..1095 : pack combined weights (key_w@conv_w | query_w@conv_w)
//                      into MFMA B-fragment order
//   block 1096       : combined bias
// ---------------------------------------------------------------------------
__global__ __launch_bounds__(256) void tp_k(
    const float* __restrict__ feats, const float* __restrict__ cw,
    const float* __restrict__ kw, const float* __restrict__ qw,
    const float* __restrict__ cb, const float* __restrict__ kb,
    const float* __restrict__ qb, unsigned short* __restrict__ fpm,
    unsigned short* __restrict__ wp, float* __restrict__ bias)
{
    const int bid = blockIdx.x;
    const int tid = threadIdx.x;

    if (bid < 520) {
        // ---- transpose/pad job ----
        const int b = bid >= 260;
        const int rem = bid - b * 260;
        const int y = rem >> 1, xseg = rem & 1;
        const int lane = tid & 63, cg = tid >> 6;
        const int x = (xseg << 6) + lane;
        const bool inter = (y >= 1 && y <= 128);
        const float* src = feats + (((size_t)b * 256) << 14) + ((y - 1) << 7) + x;
        unsigned short* orow = fpm + ((size_t)(b * 130 + y) * 130 + 1 + x) * 256;

#pragma unroll
        for (int it = 0; it < 8; ++it) {
            const int c0 = (it << 5) + (cg << 3);
            uint4 v = {0u, 0u, 0u, 0u};
            if (inter) {
                float f0 = src[(size_t)(c0 + 0) << 14], f1 = src[(size_t)(c0 + 1) << 14];
                float f2 = src[(size_t)(c0 + 2) << 14], f3 = src[(size_t)(c0 + 3) << 14];
                float f4 = src[(size_t)(c0 + 4) << 14], f5 = src[(size_t)(c0 + 5) << 14];
                float f6 = src[(size_t)(c0 + 6) << 14], f7 = src[(size_t)(c0 + 7) << 14];
                v.x = pk2(f0, f1); v.y = pk2(f2, f3); v.z = pk2(f4, f5); v.w = pk2(f6, f7);
            }
            *(uint4*)(orow + c0) = v;
        }
        if (xseg == 0) {
            uint4 z = {0u, 0u, 0u, 0u};
            if (tid < 32)
                *(uint4*)(fpm + ((size_t)(b * 130 + y) * 130 + 0) * 256 + (tid << 3)) = z;
            else if (tid < 64)
                *(uint4*)(fpm + ((size_t)(b * 130 + y) * 130 + 129) * 256 + ((tid - 32) << 3)) = z;
        }
        return;
    }

    if (bid == 1096) {
        // ---- combined bias ----
        __shared__ float cbv[128];
        if (tid < 128) cbv[tid] = cb[tid];
        __syncthreads();
        const int oc = tid & 127, isQ = tid >> 7;
        const float* wrow = (isQ ? qw : kw) + oc * 128;
        float a = isQ ? qb[oc] : kb[oc];
        for (int j = 0; j < 128; ++j) a += wrow[j] * cbv[j];
        bias[tid] = a;
        return;
    }

    // ---- weight-pack job ----
    __shared__ float cvec[128][4];
    const int g = bid - 520;
    for (int idx = tid; idx < 512; idx += 256) {
        int j = idx >> 2, q = idx & 3;
        int pair = (g << 2) + q;
        int c = pair / 9, tap = pair - c * 9;
        cvec[j][q] = cw[j * 2304 + c * 9 + tap];
    }
    __syncthreads();
    const int oc = tid & 127, isQ = tid >> 7;
    const float* wrow = (isQ ? qw : kw) + oc * 128;
    float acc0 = 0.f, acc1 = 0.f, acc2 = 0.f, acc3 = 0.f;
    for (int j = 0; j < 128; ++j) {
        float wv = wrow[j];
        acc0 += wv * cvec[j][0]; acc1 += wv * cvec[j][1];
        acc2 += wv * cvec[j][2]; acc3 += wv * cvec[j][3];
    }
    float accs[4] = {acc0, acc1, acc2, acc3};
#pragma unroll
    for (int q = 0; q < 4; ++q) {
        int pair = (g << 2) + q;
        int c = pair / 9, tap = pair - c * 9;
        int chunk = c >> 5, kg = (c >> 3) & 3, i = c & 7;
        int nf = (isQ << 3) + (oc >> 4);
        int lane = (kg << 4) + (oc & 15);
        wp[((size_t)(((chunk * 9 + tap) << 4) + nf) << 9) + (lane << 3) + i] = f2bf(accs[q]);
    }
}

// ---------------------------------------------------------------------------
// conv4_k: fused 3x3 conv -> 256 outputs via bf16 MFMA.
// 3-deep LDS staging pipeline with counted vmcnt(2) + raw s_barrier (T3/T4):
// prefetch loads stay in flight across the per-chunk barrier. Every wave
// issues exactly 2 gload_lds per stage (chunk 7 of each stage is a dummy pad
// slot) so the vmcnt immediate is wave-uniform.
// Epilogue: acc -> LDS obuf -> vectorized kT1/qT1 stores + pool2 + pool4.
// ---------------------------------------------------------------------------
__global__ __launch_bounds__(256, 2) void conv4_k(
    const unsigned short* __restrict__ fpm, const unsigned short* __restrict__ wp,
    const float* __restrict__ kqbias, unsigned short* __restrict__ kT,
    unsigned short* __restrict__ qT, unsigned short* __restrict__ kT2,
    unsigned short* __restrict__ qT2, unsigned short* __restrict__ kT3,
    unsigned short* __restrict__ qT3)
{
    __shared__ __align__(16) unsigned char abuf[3][8192];
    __shared__ __align__(16) unsigned short obuf[64 * 264];

    const int tid = threadIdx.x;
    const int w = tid >> 6, lane = tid & 63;
    const int bid = blockIdx.x;
    const int b = bid >> 8, tile = bid & 255;
    const int ty0 = (tile >> 4) << 3, tx0 = (tile & 15) << 3;
    const int r = lane & 15, g = lane >> 4;

    const int sp_sub = lane >> 2, sp_o = (lane & 3) << 4;
    const int pbase = (((r >> 3) * 10) + (r & 7)) * 64 + (g << 4);
    const unsigned char* wpB = (const unsigned char*)wp + ((w << 2) << 10) + (lane << 4);

    f32x4 acc[4][4];
#pragma unroll
    for (int mi = 0; mi < 4; ++mi)
#pragma unroll
        for (int ni = 0; ni < 4; ++ni) acc[mi][ni] = (f32x4){0.f, 0.f, 0.f, 0.f};

    // stage: 2 gload_lds per wave per chunk (i = w and w+4; i==7 is a dummy
    // pad load into abuf[buf][7K..8K) — staged bytes land in ws slack, never read)
    auto stage = [&](int chunk, int buf) {
#pragma unroll
        for (int k = 0; k < 2; ++k) {
            int i = w + (k << 2);
            int pl0 = (i << 4) + sp_sub;
            int y = (pl0 * 6554) >> 16;
            int x = pl0 - y * 10;
            const unsigned char* src = (const unsigned char*)fpm +
                (((size_t)((b * 130 + ty0 + y) * 130 + tx0 + x)) << 9) +
                (chunk << 6) + sp_o;
            gload_lds16(src, &abuf[buf][i << 10]);
        }
    };

    stage(0, 0);
    stage(1, 1);
    KBAR2();                        // stage(0) done; stage(1) stays in flight

#pragma unroll
    for (int chunk = 0; chunk < 8; ++chunk) {
        const unsigned char* ab = abuf[chunk % 3];
        const unsigned char* wbase = wpB + (size_t)chunk * 147456;
#pragma unroll
        for (int tap = 0; tap < 9; ++tap) {
            const int dy = tap / 3, dx = tap % 3;
            short8 bf[4];
#pragma unroll
            for (int ni = 0; ni < 4; ++ni)
                bf[ni] = *(const short8*)(wbase + tap * 16384 + (ni << 10));
            short8 af[4];
#pragma unroll
            for (int mi = 0; mi < 4; ++mi)
                af[mi] = *(const short8*)(ab + pbase + (((2 * mi + dy) * 10 + dx) << 6));
#pragma unroll
            for (int mi = 0; mi < 4; ++mi)
#pragma unroll
                for (int ni = 0; ni < 4; ++ni)
                    acc[mi][ni] = __builtin_amdgcn_mfma_f32_16x16x32_bf16(
                        af[mi], bf[ni], acc[mi][ni], 0, 0, 0);
        }
        if (chunk < 6) {
            stage(chunk + 2, (chunk + 2) % 3);
            KBAR2();               // stage(chunk+1) done; stage(chunk+2) in flight
        } else if (chunk == 6) {
            KBAR0();               // final drain: stage(7) done
        }
    }

    // epilogue: acc -> obuf (bf16, +bias)
    const int col = lane & 15;
    const int mrow0 = g << 2;
#pragma unroll
    for (int ni = 0; ni < 4; ++ni) {
        const int nf = (w << 2) + ni;
        const float bv = kqbias[(nf << 4) + col];
#pragma unroll
        for (int mi = 0; mi < 4; ++mi)
#pragma unroll
            for (int reg = 0; reg < 4; ++reg) {
                int m = mrow0 + reg;
                int pxl = ((2 * mi + (m >> 3)) << 3) + (m & 7);
                obuf[pxl * 264 + (nf << 4) + col] = f2bf(acc[mi][ni][reg] + bv);
            }
    }
    __syncthreads();

    // kT1/qT1: thread = (px, 64-oc quarter), 8x uint4
    {
        const int px = tid >> 2, q = tid & 3;
        const int gp = ((ty0 + (px >> 3)) << 7) + tx0 + (px & 7);
        const unsigned short* srow = obuf + px * 264 + (q << 6);
        unsigned short* dp = (q < 2)
            ? kT + ((((size_t)b << 14) + gp) << 7) + (q << 6)
            : qT + ((((size_t)b << 14) + gp) << 7) + ((q - 2) << 6);
#pragma unroll
        for (int j = 0; j < 8; ++j)
            *(uint4*)(dp + (j << 3)) = *(const uint4*)(srow + (j << 3));
    }

    // pool2: 16 pooled px x 16 oc-groups
    {
        const int pp = tid >> 4, ocg = tid & 15, oc0 = ocg << 4;
        const int py2 = pp >> 2, px2 = pp & 3;
        const int gp2 = (((ty0 >> 1) + py2) << 6) + (tx0 >> 1) + px2;
        unsigned short* dp = (oc0 < 128)
            ? kT2 + (((size_t)b * 4096 + gp2) << 7) + oc0
            : qT2 + (((size_t)b * 4096 + gp2) << 7) + (oc0 - 128);
#pragma unroll
        for (int h = 0; h < 2; ++h) {
            float s0=0,s1=0,s2=0,s3=0,s4=0,s5=0,s6=0,s7=0;
#pragma unroll
            for (int dy = 0; dy < 2; ++dy)
#pragma unroll
                for (int dx = 0; dx < 2; ++dx) {
                    int pxl = (((py2 << 1) + dy) << 3) + (px2 << 1) + dx;
                    uint4 v = *(const uint4*)(obuf + pxl * 264 + oc0 + (h << 3));
                    s0 += blo(v.x); s1 += bhi(v.x); s2 += blo(v.y); s3 += bhi(v.y);
                    s4 += blo(v.z); s5 += bhi(v.z); s6 += blo(v.w); s7 += bhi(v.w);
                }
            uint4 o;
            o.x = pk2(s0 * 0.25f, s1 * 0.25f); o.y = pk2(s2 * 0.25f, s3 * 0.25f);
            o.z = pk2(s4 * 0.25f, s5 * 0.25f); o.w = pk2(s6 * 0.25f, s7 * 0.25f);
            *(uint4*)(dp + (h << 3)) = o;
        }
    }

    // pool4: 4 pooled px x 16 oc-groups (threads 0..63)
    if (tid < 64) {
        const int pp = tid >> 4, ocg = tid & 15, oc0 = ocg << 4;
        const int py4 = pp >> 1, px4 = pp & 1;
        const int gp4 = (((ty0 >> 2) + py4) << 5) + (tx0 >> 2) + px4;
        unsigned short* dp = (oc0 < 128)
            ? kT3 + (((size_t)b * 1024 + gp4) << 7) + oc0
            : qT3 + (((size_t)b * 1024 + gp4) << 7) + (oc0 - 128);
#pragma unroll
        for (int h = 0; h < 2; ++h) {
            float s0=0,s1=0,s2=0,s3=0,s4=0,s5=0,s6=0,s7=0;
#pragma unroll
            for (int dy = 0; dy < 4; ++dy)
#pragma unroll
                for (int dx = 0; dx < 4; ++dx) {
                    int pxl = (((py4 << 2) + dy) << 3) + (px4 << 2) + dx;
                    uint4 v = *(const uint4*)(obuf + pxl * 264 + oc0 + (h << 3));
                    s0 += blo(v.x); s1 += bhi(v.x); s2 += blo(v.y); s3 += bhi(v.y);
                    s4 += blo(v.z); s5 += bhi(v.z); s6 += blo(v.w); s7 += bhi(v.w);
                }
            const float f = 0.0625f;
            uint4 o;
            o.x = pk2(s0 * f, s1 * f); o.y = pk2(s2 * f, s3 * f);
            o.z = pk2(s4 * f, s5 * f); o.w = pk2(s6 * f, s7 * f);
            *(uint4*)(dp + (h << 3)) = o;
        }
    }
}

// ---------------------------------------------------------------------------
// gdot_all_k: all 3 levels, 672 blocks x 512 thr. Index preload (8x int4),
// 7 random k-rows prefetched to regs, locals from XOR-swizzled LDS window,
// results buffered -> one coalesced float4 store per lane.
// ---------------------------------------------------------------------------
__global__ __launch_bounds__(512) void gdot_all_k(
    const unsigned short* __restrict__ qT1, const unsigned short* __restrict__ kT1,
    const unsigned short* __restrict__ qT2, const unsigned short* __restrict__ kT2,
    const unsigned short* __restrict__ qT3, const unsigned short* __restrict__ kT3,
    const int* __restrict__ i2, const int* __restrict__ i3, const int* __restrict__ i4,
    float* __restrict__ out)
{
    __shared__ __align__(16) unsigned char kwin[144 * 256];   // 36,864 B

    const int raw = blockIdx.x;
    const int bid = (raw & 7) * 84 + (raw >> 3);              // 672 = 8*84, bijective

    const unsigned short *qT, *kT;
    const int* inds;
    int n, wshift, tpbsh, twsh, off;
    if (bid < 512) {
        qT = qT1; kT = kT1; inds = i2; n = 16384; wshift = 7; tpbsh = 8; twsh = 4; off = 0;
    } else if (bid < 640) {
        qT = qT2; kT = kT2; inds = i3; n = 4096;  wshift = 6; tpbsh = 6; twsh = 3; off = 16384;
    } else {
        qT = qT3; kT = kT3; inds = i4; n = 1024;  wshift = 5; tpbsh = 4; twsh = 2; off = 20480;
    }
    const int lb   = bid - ((bid < 512) ? 0 : (bid < 640) ? 512 : 640);
    const int b    = lb >> tpbsh;
    const int tile = lb & ((1 << tpbsh) - 1);
    const int ty0  = (tile >> twsh) << 3;
    const int tx0  = (tile & ((1 << twsh) - 1)) << 3;
    const int W    = 1 << wshift, Wm1 = W - 1;
    const int ry0  = ty0 - 2, cx0 = tx0 - 2;

    const int tid   = threadIdx.x;
    const int pxl   = tid >> 3;
    const int slice = tid & 7;
    const int py = pxl >> 3, px = pxl & 7;
    const int nid = ((ty0 + py) << wshift) + tx0 + px;

    for (int idx = tid; idx < 2304; idx += 512) {
        int slot = idx >> 4, w16 = idx & 15;
        int sy = ry0 + slot / 12, sx = cx0 + slot % 12;
        sy = min(max(sy, 0), Wm1); sx = min(max(sx, 0), Wm1);
        uint4 v = *(const uint4*)(kT + ((size_t)(b * n + (sy << wshift) + sx) * 128) + (w16 << 3));
        *(uint4*)&kwin[slot * 256 + ((w16 ^ (slot & 7)) << 4)] = v;
    }

    float qr[16];
    {
        const uint4* qp = (const uint4*)(qT + ((size_t)(b * n + nid) * 128) + (slice << 4));
        uint4 q0 = qp[0], q1 = qp[1];
        qr[0] = blo(q0.x); qr[1] = bhi(q0.x); qr[2] = blo(q0.y); qr[3] = bhi(q0.y);
        qr[4] = blo(q0.z); qr[5] = bhi(q0.z); qr[6] = blo(q0.w); qr[7] = bhi(q0.w);
        qr[8] = blo(q1.x); qr[9] = bhi(q1.x); qr[10] = blo(q1.y); qr[11] = bhi(q1.y);
        qr[12] = blo(q1.z); qr[13] = bhi(q1.z); qr[14] = blo(q1.w); qr[15] = bhi(q1.w);
    }
    __syncthreads();

    const int* irow = inds + ((size_t)(b * n + nid) << 5);
    int ia[32];
    {
        const int4* ip = (const int4*)irow;
#pragma unroll
        for (int j = 0; j < 8; ++j) {
            int4 v = ip[j];
            ia[4 * j] = v.x; ia[4 * j + 1] = v.y; ia[4 * j + 2] = v.z; ia[4 * j + 3] = v.w;
        }
    }

    uint4 rk0[7], rk1[7];
#pragma unroll
    for (int rr = 0; rr < 7; ++rr) {
        const uint4* kp = (const uint4*)(kT + (((size_t)(b * n + ia[25 + rr])) << 7) + (slice << 4));
        rk0[rr] = kp[0]; rk1[rr] = kp[1];
    }

    const int w2 = slice << 1;
    float res4[4] = {0.f, 0.f, 0.f, 0.f};
    float* orow = out + (((size_t)b * NTOT + off + nid) << 5);

#pragma unroll
    for (int s = 0; s < 32; ++s) {
        uint4 k0, k1;
        if (s < 25) {
            int ind = ia[s];
            int iy = ind >> wshift, ix = ind & Wm1;
            int slot = (iy - ry0) * 12 + (ix - cx0);
            int sw = slot & 7;
            const unsigned char* base2 = kwin + slot * 256;
            k0 = *(const uint4*)(base2 + ((w2 ^ sw) << 4));
            k1 = *(const uint4*)(base2 + (((w2 + 1) ^ sw) << 4));
        } else {
            k0 = rk0[s - 25]; k1 = rk1[s - 25];
        }
        float a = qr[0] * blo(k0.x) + qr[1] * bhi(k0.x)
                + qr[2] * blo(k0.y) + qr[3] * bhi(k0.y)
                + qr[4] * blo(k0.z) + qr[5] * bhi(k0.z)
                + qr[6] * blo(k0.w) + qr[7] * bhi(k0.w)
                + qr[8] * blo(k1.x) + qr[9] * bhi(k1.x)
                + qr[10] * blo(k1.y) + qr[11] * bhi(k1.y)
                + qr[12] * blo(k1.z) + qr[13] * bhi(k1.z)
                + qr[14] * blo(k1.w) + qr[15] * bhi(k1.w);
        a += __shfl_xor(a, 1);
        a += __shfl_xor(a, 2);
        a += __shfl_xor(a, 4);
        if ((s >> 2) == slice) res4[s & 3] = a * SCALE;
    }
    *(float4*)(orow + (slice << 2)) = *(const float4*)res4;
}

// ---------------------------------------------------------------------------
extern "C" void kernel_launch(void* const* d_in, const int* in_sizes, int n_in,
                              void* d_out, int out_size, void* d_ws, size_t ws_size,
                              hipStream_t stream)
{
    const float* feats = (const float*)d_in[0];
    const float* cw    = (const float*)d_in[1];
    const float* cb    = (const float*)d_in[2];
    const float* kw    = (const float*)d_in[3];
    const float* kb    = (const float*)d_in[4];
    const float* qw    = (const float*)d_in[5];
    const float* qb    = (const float*)d_in[6];
    const int*   i2    = (const int*)d_in[7];
    const int*   i3    = (const int*)d_in[8];
    const int*   i4    = (const int*)d_in[9];
    float* out = (float*)d_out;

    char* ws = (char*)d_ws;
    unsigned short* wp   = (unsigned short*)ws;                 // 1,179,648 B
    float*          bias = (float*)(ws + 1179648);              //     1,024 B
    unsigned short* fpm  = (unsigned short*)(ws + 1180672);     // 17,305,600 B
    unsigned short* kT1  = (unsigned short*)(ws + 18624512);    // 8,388,608 B (slack above fpm)
    unsigned short* qT1  = kT1 + 4194304;
    unsigned short* kT2  = qT1 + 4194304;                       // 2,097,152 B
    unsigned short* qT2  = kT2 + 1048576;
    unsigned short* kT3  = qT2 + 1048576;                       //   524,288 B
    unsigned short* qT3  = kT3 + 262144;

    tp_k<<<dim3(1097), 256, 0, stream>>>(feats, cw, kw, qw, cb, kb, qb,
                                         fpm, wp, bias);
    conv4_k<<<dim3(512), 256, 0, stream>>>(fpm, wp, bias, kT1, qT1,
                                           kT2, qT2, kT3, qT3);
    gdot_all_k<<<dim3(672), 512, 0, stream>>>(qT1, kT1, qT2, kT2, qT3, kT3,
                                              i2, i3, i4, out);
}